// Round 4
// 477.224 us; speedup vs baseline: 1.0305x; 1.0305x over previous
//
#include <hip/hip_runtime.h>

namespace {

constexpr int NCOMP = 48;
constexpr int RESN  = 300;
constexpr int NFEAT = 27;
constexpr int NPTS  = 1000000;
constexpr int CCTOT = 3 * NCOMP;   // 144
constexpr int GRID1 = 32;          // sort cells per axis
constexpr int NBUCKET = GRID1 * GRID1 * GRID1;  // 32768

typedef _Float16 half_t;
typedef __attribute__((ext_vector_type(8))) _Float16 half8;
typedef __attribute__((ext_vector_type(8))) short          short8;   // 8 bf16 (4 VGPRs)
typedef __attribute__((ext_vector_type(8))) unsigned short ushort8;
typedef __attribute__((ext_vector_type(4))) float          floatx4;

// f32 -> bf16 round-to-nearest-even (works for all finite values incl. negatives)
__device__ __forceinline__ unsigned short f32_to_bf16(float x) {
    unsigned u = __float_as_uint(x);
    u += 0x7fffu + ((u >> 16) & 1u);
    return (unsigned short)(u >> 16);
}

// LDS row stride for the per-wave product tile: 72 bf16 = 144 B.
// Row holds 48 real comps + 16 zero-pad (K padded to 64 for 2x mfma K=32)
// + 8 unused. 144 B is 16B-aligned for ds_read_b128; row-to-row bank shift
// is 4 words -> <=2-way aliasing on both write and read patterns (free).
constexpr int SH_STRIDE = 72;

// ---------------- layout-transform kernels ----------------

// planes (3,48,300,300) fp32 -> planes_t (3,300,300,48) fp16
__global__ void transpose_planes_k(const float* __restrict__ src,
                                   half_t* __restrict__ dst) {
    int idx = blockIdx.x * blockDim.x + threadIdx.x;
    constexpr int total = 3 * RESN * RESN;
    if (idx >= total) return;
    int i   = idx / (RESN * RESN);
    int rem = idx - i * (RESN * RESN);          // y*RESN + x
    const float* s = src + (size_t)i * NCOMP * RESN * RESN + rem;
    half8* d = (half8*)(dst + (size_t)idx * NCOMP);
#pragma unroll
    for (int g = 0; g < NCOMP / 8; ++g) {
        half8 h;
#pragma unroll
        for (int k = 0; k < 8; ++k)
            h[k] = (half_t)s[(size_t)(g * 8 + k) * (RESN * RESN)];  // coalesced across lanes
        d[g] = h;
    }
}

// merged tiny setup work:
//   [0, LINES_TOT)   lines (3,48,300,1) fp32 -> lines_t (3,300,48) fp16
//   [.., +WT_TOT)    basis_W (27,144) -> Wt (144,27) fp32 (scalar fallback path)
//   [.., +WFRAG_TOT) basis_W -> MFMA B-fragment layout bf16
//                    [mode][kblk:2][n:2][lane:64][j:8]
//                    value = W[f][mode*48 + kblk*32 + 8*(lane>>4)+j]
//                    f = n*16 + (lane&15); zero when f>=27 or k>=48
//   [.., +NBUCKET)   hist zero
constexpr int LINES_TOT = 3 * RESN;            // 900
constexpr int WT_TOT    = NFEAT * CCTOT;       // 3888
constexpr int WFRAG_TOT = 3 * 2 * 2 * 64 * 8;  // 6144
constexpr int SETUP_TOT = LINES_TOT + WT_TOT + WFRAG_TOT + NBUCKET;

__global__ __launch_bounds__(256) void small_setup_k(
    const float* __restrict__ lines, const float* __restrict__ W,
    half_t* __restrict__ lt, float* __restrict__ wt,
    unsigned short* __restrict__ wfrag, int* __restrict__ hist) {
    int idx = blockIdx.x * blockDim.x + threadIdx.x;
    if (idx < LINES_TOT) {
        int i = idx / RESN;
        int y = idx - i * RESN;
        const float* s = lines + (size_t)i * NCOMP * RESN + y;
        half8* d = (half8*)(lt + (size_t)idx * NCOMP);
#pragma unroll
        for (int g = 0; g < NCOMP / 8; ++g) {
            half8 h;
#pragma unroll
            for (int k = 0; k < 8; ++k)
                h[k] = (half_t)s[(size_t)(g * 8 + k) * RESN];
            d[g] = h;
        }
        return;
    }
    idx -= LINES_TOT;
    if (idx < WT_TOT) {
        int f  = idx / CCTOT;
        int cc = idx - f * CCTOT;
        wt[(size_t)cc * NFEAT + f] = W[idx];
        return;
    }
    idx -= WT_TOT;
    if (idx < WFRAG_TOT) {
        int j    = idx & 7;
        int lane = (idx >> 3) & 63;
        int nn   = (idx >> 9) & 1;
        int kb   = (idx >> 10) & 1;
        int md   = idx >> 11;
        int f  = nn * 16 + (lane & 15);
        int kk = kb * 32 + ((lane >> 4) << 3) + j;
        float vf = 0.0f;
        if (f < NFEAT && kk < NCOMP)
            vf = W[(size_t)f * CCTOT + md * NCOMP + kk];
        wfrag[idx] = f32_to_bf16(vf);
        return;
    }
    idx -= WFRAG_TOT;
    if (hist && idx < NBUCKET) hist[idx] = 0;
}

// ---------------- counting sort by spatial cell ----------------

__device__ __forceinline__ int cell_of(float q) {
    float t = (q + 1.0f) * (0.5f * (float)GRID1);   // [0,32)
    int c = (int)t;
    return min(max(c, 0), GRID1 - 1);
}
__device__ __forceinline__ int key_of(float q0, float q1, float q2) {
    return (cell_of(q0) * GRID1 + cell_of(q1)) * GRID1 + cell_of(q2);
}

__global__ __launch_bounds__(256) void hist_k(const float* __restrict__ xyz,
                                              int* __restrict__ hist) {
    int p = blockIdx.x * blockDim.x + threadIdx.x;
    if (p >= NPTS) return;
    float q0 = xyz[3 * (size_t)p + 0];
    float q1 = xyz[3 * (size_t)p + 1];
    float q2 = xyz[3 * (size_t)p + 2];
    atomicAdd(&hist[key_of(q0, q1, q2)], 1);
}

__global__ __launch_bounds__(1024) void scan_k(const int* __restrict__ hist,
                                               int* __restrict__ start) {
    __shared__ int part[1024];
    int t = threadIdx.x;
    int base = t * (NBUCKET / 1024);
    int s = 0;
#pragma unroll 4
    for (int j = 0; j < NBUCKET / 1024; ++j) s += hist[base + j];
    part[t] = s;
    __syncthreads();
    for (int off = 1; off < 1024; off <<= 1) {
        int v = (t >= off) ? part[t - off] : 0;
        __syncthreads();
        part[t] += v;
        __syncthreads();
    }
    int run = (t == 0) ? 0 : part[t - 1];
    for (int j = 0; j < NBUCKET / 1024; ++j) {
        start[base + j] = run;
        run += hist[base + j];
    }
}

__global__ __launch_bounds__(256) void scatter_k(const float* __restrict__ xyz,
                                                 int* __restrict__ start,
                                                 float4* __restrict__ xyzs) {
    int p = blockIdx.x * blockDim.x + threadIdx.x;
    if (p >= NPTS) return;
    float q0 = xyz[3 * (size_t)p + 0];
    float q1 = xyz[3 * (size_t)p + 1];
    float q2 = xyz[3 * (size_t)p + 2];
    int slot = atomicAdd(&start[key_of(q0, q1, q2)], 1);
    float4 v;
    v.x = q0; v.y = q1; v.z = q2; v.w = __int_as_float(p);
    xyzs[slot] = v;
}

// ---------------- MFMA main kernel ----------------

// interpolate one mode for this lane's point; write 48 bf16 products to its LDS row
__device__ __forceinline__ void produce_mode(float gx, float gy, float gl,
                                             const half_t* __restrict__ pt_i,
                                             const half_t* __restrict__ lt_i,
                                             unsigned short* __restrict__ shrow) {
    float x = (gx + 1.0f) * 0.5f * (float)(RESN - 1);
    float y = (gy + 1.0f) * 0.5f * (float)(RESN - 1);
    float l = (gl + 1.0f) * 0.5f * (float)(RESN - 1);
    float x0f = floorf(x), y0f = floorf(y), l0f = floorf(l);
    float wx = x - x0f, wy = y - y0f, wl = l - l0f;
    int x0 = max(0, min((int)x0f, RESN - 1));
    int y0 = max(0, min((int)y0f, RESN - 1));
    int l0 = max(0, min((int)l0f, RESN - 1));
    int x1 = min(x0 + 1, RESN - 1);
    int y1 = min(y0 + 1, RESN - 1);
    int l1 = min(l0 + 1, RESN - 1);
    float w00 = (1.0f - wy) * (1.0f - wx);
    float w01 = (1.0f - wy) * wx;
    float w10 = wy * (1.0f - wx);
    float w11 = wy * wx;
    float wl0 = 1.0f - wl;
    float wl1 = wl;

    const half8* p00 = (const half8*)(pt_i + ((size_t)y0 * RESN + x0) * NCOMP);
    const half8* p01 = (const half8*)(pt_i + ((size_t)y0 * RESN + x1) * NCOMP);
    const half8* p10 = (const half8*)(pt_i + ((size_t)y1 * RESN + x0) * NCOMP);
    const half8* p11 = (const half8*)(pt_i + ((size_t)y1 * RESN + x1) * NCOMP);
    const half8* L0  = (const half8*)(lt_i + (size_t)l0 * NCOMP);
    const half8* L1  = (const half8*)(lt_i + (size_t)l1 * NCOMP);

#pragma unroll 2
    for (int g = 0; g < NCOMP / 8; ++g) {
        half8 a = p00[g], b = p01[g], c = p10[g], d = p11[g];
        half8 e0 = L0[g], e1 = L1[g];
        ushort8 h;
#pragma unroll
        for (int j = 0; j < 8; ++j) {
            float pv = w00 * (float)a[j] + w01 * (float)b[j]
                     + w10 * (float)c[j] + w11 * (float)d[j];
            float lv = wl0 * (float)e0[j] + wl1 * (float)e1[j];
            h[j] = f32_to_bf16(pv * lv);
        }
        *(ushort8*)(shrow + g * 8) = h;
    }
}

// one mode's worth of MFMAs over the wave's 64-point LDS tile.
// K=48 padded to 64 -> two 16x16x32_bf16 per (m,n) — the guide's end-to-end
// verified instruction (m89/m91/m92 layouts), frag type short8.
__device__ __forceinline__ void mfma_phase(const unsigned short* __restrict__ shw, int ln,
                                           short8 blo0, short8 blo1,
                                           short8 bhi0, short8 bhi1,
                                           floatx4 acc[4][2]) {
#pragma unroll
    for (int m = 0; m < 4; ++m) {
        const unsigned short* rb = shw + (size_t)(m * 16 + (ln & 15)) * SH_STRIDE;
        short8 alo = *(const short8*)(rb + ((ln >> 4) * 8));        // k  0..31
        short8 ahi = *(const short8*)(rb + 32 + ((ln >> 4) * 8));   // k 32..63 (48+ = 0)
        acc[m][0] = __builtin_amdgcn_mfma_f32_16x16x32_bf16(alo, blo0, acc[m][0], 0, 0, 0);
        acc[m][0] = __builtin_amdgcn_mfma_f32_16x16x32_bf16(ahi, bhi0, acc[m][0], 0, 0, 0);
        acc[m][1] = __builtin_amdgcn_mfma_f32_16x16x32_bf16(alo, blo1, acc[m][1], 0, 0, 0);
        acc[m][1] = __builtin_amdgcn_mfma_f32_16x16x32_bf16(ahi, bhi1, acc[m][1], 0, 0, 0);
    }
}

__global__ __launch_bounds__(256) void tensor_vm_mfma_kernel(
    const float4* __restrict__ xyzs,
    const half_t* __restrict__ pt,
    const half_t* __restrict__ lt,
    const unsigned short* __restrict__ wfrag,
    float* __restrict__ out) {
    __shared__ unsigned short sh[4][64][SH_STRIDE];   // per-wave product tiles, 36 KB
    __shared__ int            sperm[4][64];

    const int tid = threadIdx.x;
    const int w  = tid >> 6;
    const int ln = tid & 63;
    const int gidx = blockIdx.x * 256 + tid;
    const int i = min(gidx, NPTS - 1);        // clamp: full block reaches barriers
    float4 v = xyzs[i];
    const float q0 = v.x, q1 = v.y, q2 = v.z;
    sperm[w][ln] = __float_as_int(v.w);

    floatx4 acc[4][2];
    const floatx4 z = {0.f, 0.f, 0.f, 0.f};
#pragma unroll
    for (int m = 0; m < 4; ++m) { acc[m][0] = z; acc[m][1] = z; }

    constexpr size_t PSZ = (size_t)RESN * RESN * NCOMP;
    constexpr size_t LSZ = (size_t)RESN * NCOMP;

    unsigned short* shrow = &sh[w][ln][0];
    const unsigned short* shw = &sh[w][0][0];

    // zero the K-pad (comps 48..63) of this lane's row, once; produce_mode
    // only writes 0..47, so the pad stays zero across all three modes.
    {
        ushort8 hz = {0, 0, 0, 0, 0, 0, 0, 0};
        *(ushort8*)(shrow + 48) = hz;
        *(ushort8*)(shrow + 56) = hz;
    }

    // PLANE_AX = ((2,1),(2,0),(1,0)); line axis = mode index
    const float gxs[3] = {q2, q2, q1};
    const float gys[3] = {q1, q0, q0};
    const float gls[3] = {q0, q1, q2};

#pragma unroll
    for (int md = 0; md < 3; ++md) {
        // B-fragments for this mode (L2-hot 12 KB), issue early
        const unsigned short* wfb = wfrag + (size_t)md * 2048 + (size_t)ln * 8;
        short8 blo0 = *(const short8*)(wfb);           // kblk=0, n=0
        short8 blo1 = *(const short8*)(wfb + 512);     // kblk=0, n=1
        short8 bhi0 = *(const short8*)(wfb + 1024);    // kblk=1, n=0
        short8 bhi1 = *(const short8*)(wfb + 1536);    // kblk=1, n=1

        produce_mode(gxs[md], gys[md], gls[md], pt + md * PSZ, lt + md * LSZ, shrow);
        __syncthreads();
        mfma_phase(shw, ln, blo0, blo1, bhi0, bhi1, acc);
        __syncthreads();
    }

    // epilogue: D layout col=lane&15 (feature), row=(lane>>4)*4+reg (point)
    const int q = ln >> 4;
    const int c = ln & 15;
    const int blockBase = blockIdx.x * 256 + w * 64;
#pragma unroll
    for (int m = 0; m < 4; ++m) {
#pragma unroll
        for (int r = 0; r < 4; ++r) {
            const int pl = m * 16 + q * 4 + r;
            if (blockBase + pl < NPTS) {
                const int pp = sperm[w][pl];
                float* o = out + (size_t)pp * NFEAT + c;
                o[0] = acc[m][0][r];
                if (c < NFEAT - 16) o[16] = acc[m][1][r];
            }
        }
    }
}

// ---------------- scalar fallbacks ----------------

__device__ __forceinline__ void accum_mode(float gx, float gy, float gl,
                                           const half_t* __restrict__ pt_i,
                                           const half_t* __restrict__ lt_i,
                                           const float* __restrict__ wt_i,
                                           float* __restrict__ acc) {
    float x = (gx + 1.0f) * 0.5f * (float)(RESN - 1);
    float y = (gy + 1.0f) * 0.5f * (float)(RESN - 1);
    float l = (gl + 1.0f) * 0.5f * (float)(RESN - 1);
    float x0f = floorf(x), y0f = floorf(y), l0f = floorf(l);
    float wx = x - x0f, wy = y - y0f, wl = l - l0f;
    int x0 = (int)x0f; x0 = max(0, min(x0, RESN - 1));
    int y0 = (int)y0f; y0 = max(0, min(y0, RESN - 1));
    int l0 = (int)l0f; l0 = max(0, min(l0, RESN - 1));
    int x1 = min(x0 + 1, RESN - 1);
    int y1 = min(y0 + 1, RESN - 1);
    int l1 = min(l0 + 1, RESN - 1);
    float w00 = (1.0f - wy) * (1.0f - wx);
    float w01 = (1.0f - wy) * wx;
    float w10 = wy * (1.0f - wx);
    float w11 = wy * wx;
    float wl0 = 1.0f - wl;
    float wl1 = wl;
    const half8* p00 = (const half8*)(pt_i + ((size_t)y0 * RESN + x0) * NCOMP);
    const half8* p01 = (const half8*)(pt_i + ((size_t)y0 * RESN + x1) * NCOMP);
    const half8* p10 = (const half8*)(pt_i + ((size_t)y1 * RESN + x0) * NCOMP);
    const half8* p11 = (const half8*)(pt_i + ((size_t)y1 * RESN + x1) * NCOMP);
    const half8* L0  = (const half8*)(lt_i + (size_t)l0 * NCOMP);
    const half8* L1  = (const half8*)(lt_i + (size_t)l1 * NCOMP);
#pragma unroll 2
    for (int g = 0; g < NCOMP / 8; ++g) {
        half8 a = p00[g], b = p01[g], c = p10[g], d = p11[g];
        half8 e0 = L0[g], e1 = L1[g];
#pragma unroll
        for (int j = 0; j < 8; ++j) {
            float pv = w00 * (float)a[j] + w01 * (float)b[j]
                     + w10 * (float)c[j] + w11 * (float)d[j];
            float lv = wl0 * (float)e0[j] + wl1 * (float)e1[j];
            float pr = pv * lv;
            const float* wrow = wt_i + (size_t)(8 * g + j) * NFEAT;
#pragma unroll
            for (int f = 0; f < NFEAT; ++f)
                acc[f] += pr * wrow[f];
        }
    }
}

__global__ __launch_bounds__(256) void tensor_vm_kernel(
    const float* __restrict__ xyz,
    const half_t* __restrict__ pt,
    const half_t* __restrict__ lt,
    const float* __restrict__ wt,
    float* __restrict__ out) {
    int p = blockIdx.x * blockDim.x + threadIdx.x;
    if (p >= NPTS) return;
    float q0 = xyz[3 * (size_t)p + 0];
    float q1 = xyz[3 * (size_t)p + 1];
    float q2 = xyz[3 * (size_t)p + 2];
    float acc[NFEAT];
#pragma unroll
    for (int f = 0; f < NFEAT; ++f) acc[f] = 0.0f;
    constexpr size_t PSZ = (size_t)RESN * RESN * NCOMP;
    constexpr size_t LSZ = (size_t)RESN * NCOMP;
    constexpr int    WSZ = NCOMP * NFEAT;
    accum_mode(q2, q1, q0, pt,           lt,           wt,           acc);
    accum_mode(q2, q0, q1, pt + PSZ,     lt + LSZ,     wt + WSZ,     acc);
    accum_mode(q1, q0, q2, pt + 2 * PSZ, lt + 2 * LSZ, wt + 2 * WSZ, acc);
    float* o = out + (size_t)p * NFEAT;
#pragma unroll
    for (int f = 0; f < NFEAT; ++f) o[f] = acc[f];
}

__global__ __launch_bounds__(256) void tensor_vm_naive_kernel(
    const float* __restrict__ xyz,
    const float* __restrict__ planes,
    const float* __restrict__ lines,
    const float* __restrict__ W,
    float* __restrict__ out) {
    int p = blockIdx.x * blockDim.x + threadIdx.x;
    if (p >= NPTS) return;
    float q[3];
    q[0] = xyz[3 * (size_t)p + 0];
    q[1] = xyz[3 * (size_t)p + 1];
    q[2] = xyz[3 * (size_t)p + 2];
    float acc[NFEAT];
    for (int f = 0; f < NFEAT; ++f) acc[f] = 0.0f;
    const int AX[3] = {2, 2, 1};
    const int BX[3] = {1, 0, 0};
    for (int i = 0; i < 3; ++i) {
        float gx = q[AX[i]], gy = q[BX[i]], gl = q[i];
        float x = (gx + 1.0f) * 0.5f * (float)(RESN - 1);
        float y = (gy + 1.0f) * 0.5f * (float)(RESN - 1);
        float l = (gl + 1.0f) * 0.5f * (float)(RESN - 1);
        float x0f = floorf(x), y0f = floorf(y), l0f = floorf(l);
        float wx = x - x0f, wy = y - y0f, wl = l - l0f;
        int x0 = max(0, min((int)x0f, RESN - 1));
        int y0 = max(0, min((int)y0f, RESN - 1));
        int l0 = max(0, min((int)l0f, RESN - 1));
        int x1 = min(x0 + 1, RESN - 1);
        int y1 = min(y0 + 1, RESN - 1);
        int l1 = min(l0 + 1, RESN - 1);
        float w00 = (1.0f - wy) * (1.0f - wx);
        float w01 = (1.0f - wy) * wx;
        float w10 = wy * (1.0f - wx);
        float w11 = wy * wx;
        const float* pl = planes + (size_t)i * NCOMP * RESN * RESN;
        const float* ln = lines + (size_t)i * NCOMP * RESN;
        for (int c = 0; c < NCOMP; ++c) {
            const float* plc = pl + (size_t)c * RESN * RESN;
            float v00 = plc[(size_t)y0 * RESN + x0];
            float v01 = plc[(size_t)y0 * RESN + x1];
            float v10 = plc[(size_t)y1 * RESN + x0];
            float v11 = plc[(size_t)y1 * RESN + x1];
            float pv = w00 * v00 + w01 * v01 + w10 * v10 + w11 * v11;
            float lv = (1.0f - wl) * ln[(size_t)c * RESN + l0] + wl * ln[(size_t)c * RESN + l1];
            float pr = pv * lv;
            int cc = i * NCOMP + c;
            for (int f = 0; f < NFEAT; ++f)
                acc[f] += pr * W[(size_t)f * CCTOT + cc];
        }
    }
    float* o = out + (size_t)p * NFEAT;
    for (int f = 0; f < NFEAT; ++f) o[f] = acc[f];
}

}  // namespace

extern "C" void kernel_launch(void* const* d_in, const int* in_sizes, int n_in,
                              void* d_out, int out_size, void* d_ws, size_t ws_size,
                              hipStream_t stream) {
    (void)in_sizes; (void)n_in; (void)out_size;
    const float* xyz    = (const float*)d_in[0];
    const float* planes = (const float*)d_in[1];
    const float* lines  = (const float*)d_in[2];
    const float* W      = (const float*)d_in[3];
    float* out = (float*)d_out;

    constexpr size_t PT_HALVES   = (size_t)3 * RESN * RESN * NCOMP;  // 12,960,000
    constexpr size_t LT_HALVES   = (size_t)3 * RESN * NCOMP;         // 43,200
    constexpr size_t WT_FLOATS   = (size_t)CCTOT * NFEAT;            // 3,888

    // ws layout: [wt fp32][wfrag bf16][pt fp16][lt fp16][hist][start][xyzs]
    constexpr size_t WT_BYTES    = WT_FLOATS * sizeof(float);        // 15,552
    constexpr size_t WFRAG_BYTES = (size_t)WFRAG_TOT * 2;            // 12,288
    constexpr size_t PT_BYTES    = PT_HALVES * sizeof(half_t);       // 25,920,000
    constexpr size_t LT_BYTES    = LT_HALVES * sizeof(half_t);       // 86,400
    constexpr size_t HIST_BYTES  = (size_t)NBUCKET * sizeof(int);    // 131,072
    constexpr size_t XYZS_BYTES  = (size_t)NPTS * sizeof(float4);    // 16,000,000
    constexpr size_t NEED_PLAIN  = WT_BYTES + WFRAG_BYTES + PT_BYTES + LT_BYTES;
    constexpr size_t NEED_SORT   = NEED_PLAIN + 2 * HIST_BYTES + XYZS_BYTES;

    if (ws_size >= NEED_PLAIN) {
        float*          wt    = (float*)d_ws;
        unsigned short* wfrag = (unsigned short*)((char*)d_ws + WT_BYTES);
        half_t*         pt    = (half_t*)((char*)d_ws + WT_BYTES + WFRAG_BYTES);
        half_t*         lt    = (half_t*)((char*)d_ws + WT_BYTES + WFRAG_BYTES + PT_BYTES);
        int* hist = nullptr;
        int* start = nullptr;
        float4* xyzs = nullptr;
        if (ws_size >= NEED_SORT) {
            hist  = (int*)((char*)d_ws + NEED_PLAIN);
            start = (int*)((char*)d_ws + NEED_PLAIN + HIST_BYTES);
            xyzs  = (float4*)((char*)d_ws + NEED_PLAIN + 2 * HIST_BYTES);
        }
        {
            constexpr int total = 3 * RESN * RESN;
            transpose_planes_k<<<(total + 255) / 256, 256, 0, stream>>>(planes, pt);
        }
        small_setup_k<<<(SETUP_TOT + 255) / 256, 256, 0, stream>>>(
            lines, W, lt, wt, wfrag, hist);
        if (ws_size >= NEED_SORT) {
            hist_k<<<(NPTS + 255) / 256, 256, 0, stream>>>(xyz, hist);
            scan_k<<<1, 1024, 0, stream>>>(hist, start);
            scatter_k<<<(NPTS + 255) / 256, 256, 0, stream>>>(xyz, start, xyzs);
            tensor_vm_mfma_kernel<<<(NPTS + 255) / 256, 256, 0, stream>>>(
                xyzs, pt, lt, wfrag, out);
        } else {
            tensor_vm_kernel<<<(NPTS + 255) / 256, 256, 0, stream>>>(xyz, pt, lt, wt, out);
        }
    } else {
        tensor_vm_naive_kernel<<<(NPTS + 255) / 256, 256, 0, stream>>>(xyz, planes, lines, W, out);
    }
}

// Round 5
// 457.375 us; speedup vs baseline: 1.0753x; 1.0434x over previous
//
#include <hip/hip_runtime.h>

namespace {

constexpr int NCOMP = 48;
constexpr int RESN  = 300;
constexpr int NFEAT = 27;
constexpr int NPTS  = 1000000;
constexpr int CCTOT = 3 * NCOMP;   // 144
constexpr int GRID1 = 32;          // sort cells per axis
constexpr int NBUCKET = GRID1 * GRID1 * GRID1;  // 32768

typedef _Float16 half_t;
typedef __attribute__((ext_vector_type(8))) _Float16 half8;
typedef __attribute__((ext_vector_type(8))) short          short8;   // 8 bf16 (4 VGPRs)
typedef __attribute__((ext_vector_type(8))) unsigned short ushort8;
typedef __attribute__((ext_vector_type(4))) float          floatx4;

// f32 -> bf16 round-to-nearest-even
__device__ __forceinline__ unsigned short f32_to_bf16(float x) {
    unsigned u = __float_as_uint(x);
    u += 0x7fffu + ((u >> 16) & 1u);
    return (unsigned short)(u >> 16);
}

// LDS row stride: 72 bf16 = 144 B (16B-aligned; 4-bank row shift -> ~2-way, free;
// measured conflicts 1.5M ~= 2.4us/CU -> not worth further fixing).
constexpr int SH_STRIDE = 72;

// ---------------- fused front-end kernel ----------------
// Block ranges (all independent work; hist[] is pre-zeroed by a memset node):
//   [0, TP_BLOCKS)                planes (3,48,300,300) fp32 -> (3,300,300,48) fp16
//   [TP_BLOCKS, +SU_BLOCKS)       lines transpose + Wt + W MFMA B-fragments
//   [TP_BLOCKS+SU_BLOCKS, +HB)    histogram of xyz cell keys (atomics)
constexpr int TP_TOTAL  = 3 * RESN * RESN;          // 270000
constexpr int TP_BLOCKS = (TP_TOTAL + 255) / 256;   // 1055
constexpr int LINES_TOT = 3 * RESN;                 // 900
constexpr int WT_TOT    = NFEAT * CCTOT;            // 3888
constexpr int WFRAG_TOT = 3 * 2 * 2 * 64 * 8;       // 6144
constexpr int SU_TOTAL  = LINES_TOT + WT_TOT + WFRAG_TOT;  // 10932
constexpr int SU_BLOCKS = (SU_TOTAL + 255) / 256;   // 43
constexpr int HB_BLOCKS = (NPTS + 255) / 256;       // 3907

__device__ __forceinline__ int cell_of(float q) {
    float t = (q + 1.0f) * (0.5f * (float)GRID1);   // [0,32)
    int c = (int)t;
    return min(max(c, 0), GRID1 - 1);
}
__device__ __forceinline__ int key_of(float q0, float q1, float q2) {
    return (cell_of(q0) * GRID1 + cell_of(q1)) * GRID1 + cell_of(q2);
}

__global__ __launch_bounds__(256) void fused_front_k(
    const float* __restrict__ planes, const float* __restrict__ lines,
    const float* __restrict__ W, const float* __restrict__ xyz,
    half_t* __restrict__ pt, half_t* __restrict__ lt,
    float* __restrict__ wt, unsigned short* __restrict__ wfrag,
    int* __restrict__ hist) {
    int b = blockIdx.x;
    if (b < TP_BLOCKS) {
        int idx = b * 256 + threadIdx.x;
        if (idx >= TP_TOTAL) return;
        int i   = idx / (RESN * RESN);
        int rem = idx - i * (RESN * RESN);          // y*RESN + x
        const float* s = planes + (size_t)i * NCOMP * RESN * RESN + rem;
        half8* d = (half8*)(pt + (size_t)idx * NCOMP);
#pragma unroll
        for (int g = 0; g < NCOMP / 8; ++g) {
            half8 h;
#pragma unroll
            for (int k = 0; k < 8; ++k)
                h[k] = (half_t)s[(size_t)(g * 8 + k) * (RESN * RESN)];  // coalesced across lanes
            d[g] = h;
        }
        return;
    }
    if (b < TP_BLOCKS + SU_BLOCKS) {
        int idx = (b - TP_BLOCKS) * 256 + threadIdx.x;
        if (idx < LINES_TOT) {
            int i = idx / RESN;
            int y = idx - i * RESN;
            const float* s = lines + (size_t)i * NCOMP * RESN + y;
            half8* d = (half8*)(lt + (size_t)idx * NCOMP);
#pragma unroll
            for (int g = 0; g < NCOMP / 8; ++g) {
                half8 h;
#pragma unroll
                for (int k = 0; k < 8; ++k)
                    h[k] = (half_t)s[(size_t)(g * 8 + k) * RESN];
                d[g] = h;
            }
            return;
        }
        idx -= LINES_TOT;
        if (idx < WT_TOT) {
            int f  = idx / CCTOT;
            int cc = idx - f * CCTOT;
            wt[(size_t)cc * NFEAT + f] = W[idx];
            return;
        }
        idx -= WT_TOT;
        if (idx < WFRAG_TOT) {
            // [mode][kblk:2][n:2][lane:64][j:8]; value = W[f][mode*48 + kblk*32 + 8*(lane>>4)+j]
            int j    = idx & 7;
            int lane = (idx >> 3) & 63;
            int nn   = (idx >> 9) & 1;
            int kb   = (idx >> 10) & 1;
            int md   = idx >> 11;
            int f  = nn * 16 + (lane & 15);
            int kk = kb * 32 + ((lane >> 4) << 3) + j;
            float vf = 0.0f;
            if (f < NFEAT && kk < NCOMP)
                vf = W[(size_t)f * CCTOT + md * NCOMP + kk];
            wfrag[idx] = f32_to_bf16(vf);
        }
        return;
    }
    // histogram
    int p = (b - TP_BLOCKS - SU_BLOCKS) * 256 + threadIdx.x;
    if (p >= NPTS || !hist) return;
    float q0 = xyz[3 * (size_t)p + 0];
    float q1 = xyz[3 * (size_t)p + 1];
    float q2 = xyz[3 * (size_t)p + 2];
    atomicAdd(&hist[key_of(q0, q1, q2)], 1);
}

// ---------------- counting sort: scan + scatter ----------------

__global__ __launch_bounds__(1024) void scan_k(const int* __restrict__ hist,
                                               int* __restrict__ start) {
    __shared__ int part[1024];
    int t = threadIdx.x;
    int base = t * (NBUCKET / 1024);
    int s = 0;
#pragma unroll 4
    for (int j = 0; j < NBUCKET / 1024; ++j) s += hist[base + j];
    part[t] = s;
    __syncthreads();
    for (int off = 1; off < 1024; off <<= 1) {
        int v = (t >= off) ? part[t - off] : 0;
        __syncthreads();
        part[t] += v;
        __syncthreads();
    }
    int run = (t == 0) ? 0 : part[t - 1];
    for (int j = 0; j < NBUCKET / 1024; ++j) {
        start[base + j] = run;
        run += hist[base + j];
    }
}

__global__ __launch_bounds__(256) void scatter_k(const float* __restrict__ xyz,
                                                 int* __restrict__ start,
                                                 float4* __restrict__ xyzs) {
    int p = blockIdx.x * blockDim.x + threadIdx.x;
    if (p >= NPTS) return;
    float q0 = xyz[3 * (size_t)p + 0];
    float q1 = xyz[3 * (size_t)p + 1];
    float q2 = xyz[3 * (size_t)p + 2];
    int slot = atomicAdd(&start[key_of(q0, q1, q2)], 1);
    float4 v;
    v.x = q0; v.y = q1; v.z = q2; v.w = __int_as_float(p);
    xyzs[slot] = v;
}

// ---------------- MFMA main kernel ----------------

// interpolate one mode for this lane's point; write 48 bf16 products to its LDS row
__device__ __forceinline__ void produce_mode(float gx, float gy, float gl,
                                             const half_t* __restrict__ pt_i,
                                             const half_t* __restrict__ lt_i,
                                             unsigned short* __restrict__ shrow) {
    float x = (gx + 1.0f) * 0.5f * (float)(RESN - 1);
    float y = (gy + 1.0f) * 0.5f * (float)(RESN - 1);
    float l = (gl + 1.0f) * 0.5f * (float)(RESN - 1);
    float x0f = floorf(x), y0f = floorf(y), l0f = floorf(l);
    float wx = x - x0f, wy = y - y0f, wl = l - l0f;
    int x0 = max(0, min((int)x0f, RESN - 1));
    int y0 = max(0, min((int)y0f, RESN - 1));
    int l0 = max(0, min((int)l0f, RESN - 1));
    int x1 = min(x0 + 1, RESN - 1);
    int y1 = min(y0 + 1, RESN - 1);
    int l1 = min(l0 + 1, RESN - 1);
    float w00 = (1.0f - wy) * (1.0f - wx);
    float w01 = (1.0f - wy) * wx;
    float w10 = wy * (1.0f - wx);
    float w11 = wy * wx;
    float wl0 = 1.0f - wl;
    float wl1 = wl;

    const half8* p00 = (const half8*)(pt_i + ((size_t)y0 * RESN + x0) * NCOMP);
    const half8* p01 = (const half8*)(pt_i + ((size_t)y0 * RESN + x1) * NCOMP);
    const half8* p10 = (const half8*)(pt_i + ((size_t)y1 * RESN + x0) * NCOMP);
    const half8* p11 = (const half8*)(pt_i + ((size_t)y1 * RESN + x1) * NCOMP);
    const half8* L0  = (const half8*)(lt_i + (size_t)l0 * NCOMP);
    const half8* L1  = (const half8*)(lt_i + (size_t)l1 * NCOMP);

#pragma unroll 2
    for (int g = 0; g < NCOMP / 8; ++g) {
        half8 a = p00[g], b = p01[g], c = p10[g], d = p11[g];
        half8 e0 = L0[g], e1 = L1[g];
        ushort8 h;
#pragma unroll
        for (int j = 0; j < 8; ++j) {
            float pv = w00 * (float)a[j] + w01 * (float)b[j]
                     + w10 * (float)c[j] + w11 * (float)d[j];
            float lv = wl0 * (float)e0[j] + wl1 * (float)e1[j];
            h[j] = f32_to_bf16(pv * lv);
        }
        *(ushort8*)(shrow + g * 8) = h;
    }
}

// one mode's worth of MFMAs over the wave's 64-point LDS tile.
// K=48 padded to 64 -> two 16x16x32_bf16 per (m,n).
__device__ __forceinline__ void mfma_phase(const unsigned short* __restrict__ shw, int ln,
                                           short8 blo0, short8 blo1,
                                           short8 bhi0, short8 bhi1,
                                           floatx4 acc[4][2]) {
#pragma unroll
    for (int m = 0; m < 4; ++m) {
        const unsigned short* rb = shw + (size_t)(m * 16 + (ln & 15)) * SH_STRIDE;
        short8 alo = *(const short8*)(rb + ((ln >> 4) * 8));        // k  0..31
        short8 ahi = *(const short8*)(rb + 32 + ((ln >> 4) * 8));   // k 32..63 (48+ = 0)
        acc[m][0] = __builtin_amdgcn_mfma_f32_16x16x32_bf16(alo, blo0, acc[m][0], 0, 0, 0);
        acc[m][0] = __builtin_amdgcn_mfma_f32_16x16x32_bf16(ahi, bhi0, acc[m][0], 0, 0, 0);
        acc[m][1] = __builtin_amdgcn_mfma_f32_16x16x32_bf16(alo, blo1, acc[m][1], 0, 0, 0);
        acc[m][1] = __builtin_amdgcn_mfma_f32_16x16x32_bf16(ahi, bhi1, acc[m][1], 0, 0, 0);
    }
}

// 128-thread blocks (2 waves): halves barrier coupling vs 4 waves while keeping
// the 16 waves/CU floor (8 blocks x 2 waves; LDS 18944 B/block).
constexpr int MAIN_BLK = 128;
constexpr int MAIN_NWG = (NPTS + MAIN_BLK - 1) / MAIN_BLK;   // 7813

// bijective XCD-chunked swizzle (m204): consecutive data chunks land on one XCD
// so sorted neighbors share plane rows in that XCD's 4MB L2.
__device__ __forceinline__ int swz_main(int orig) {
    constexpr int Q = MAIN_NWG / 8, R = MAIN_NWG % 8;   // 976, 5
    int x = orig & 7, p = orig >> 3;
    return (x < R ? x * (Q + 1) : R * (Q + 1) + (x - R) * Q) + p;
}

__global__ __launch_bounds__(MAIN_BLK) void tensor_vm_mfma_kernel(
    const float4* __restrict__ xyzs,
    const half_t* __restrict__ pt,
    const half_t* __restrict__ lt,
    const unsigned short* __restrict__ wfrag,
    float* __restrict__ out) {
    __shared__ unsigned short sh[2][64][SH_STRIDE];   // per-wave product tiles, 18 KB
    __shared__ int            sperm[2][64];

    const int bid = swz_main(blockIdx.x);
    const int tid = threadIdx.x;
    const int w  = tid >> 6;
    const int ln = tid & 63;
    const int gidx = bid * MAIN_BLK + tid;
    const int i = min(gidx, NPTS - 1);        // clamp: full block reaches barriers
    float4 v = xyzs[i];
    const float q0 = v.x, q1 = v.y, q2 = v.z;
    sperm[w][ln] = __float_as_int(v.w);

    floatx4 acc[4][2];
    const floatx4 z = {0.f, 0.f, 0.f, 0.f};
#pragma unroll
    for (int m = 0; m < 4; ++m) { acc[m][0] = z; acc[m][1] = z; }

    constexpr size_t PSZ = (size_t)RESN * RESN * NCOMP;
    constexpr size_t LSZ = (size_t)RESN * NCOMP;

    unsigned short* shrow = &sh[w][ln][0];
    const unsigned short* shw = &sh[w][0][0];

    // zero the K-pad (comps 48..63) once; produce_mode only writes 0..47.
    {
        ushort8 hz = {0, 0, 0, 0, 0, 0, 0, 0};
        *(ushort8*)(shrow + 48) = hz;
        *(ushort8*)(shrow + 56) = hz;
    }

    // PLANE_AX = ((2,1),(2,0),(1,0)); line axis = mode index
    const float gxs[3] = {q2, q2, q1};
    const float gys[3] = {q1, q0, q0};
    const float gls[3] = {q0, q1, q2};

#pragma unroll
    for (int md = 0; md < 3; ++md) {
        // B-fragments for this mode (L2-hot 12 KB), issue early
        const unsigned short* wfb = wfrag + (size_t)md * 2048 + (size_t)ln * 8;
        short8 blo0 = *(const short8*)(wfb);           // kblk=0, n=0
        short8 blo1 = *(const short8*)(wfb + 512);     // kblk=0, n=1
        short8 bhi0 = *(const short8*)(wfb + 1024);    // kblk=1, n=0
        short8 bhi1 = *(const short8*)(wfb + 1536);    // kblk=1, n=1

        produce_mode(gxs[md], gys[md], gls[md], pt + md * PSZ, lt + md * LSZ, shrow);
        __syncthreads();
        mfma_phase(shw, ln, blo0, blo1, bhi0, bhi1, acc);
        if (md != 2) __syncthreads();     // protect tile before next produce
    }

    // epilogue: D layout col=lane&15 (feature), row=(lane>>4)*4+reg (point)
    const int q = ln >> 4;
    const int c = ln & 15;
    const int blockBase = bid * MAIN_BLK + w * 64;
#pragma unroll
    for (int m = 0; m < 4; ++m) {
#pragma unroll
        for (int r = 0; r < 4; ++r) {
            const int pl = m * 16 + q * 4 + r;
            if (blockBase + pl < NPTS) {
                const int pp = sperm[w][pl];
                float* o = out + (size_t)pp * NFEAT + c;
                o[0] = acc[m][0][r];
                if (c < NFEAT - 16) o[16] = acc[m][1][r];
            }
        }
    }
}

// ---------------- scalar fallbacks ----------------

__device__ __forceinline__ void accum_mode(float gx, float gy, float gl,
                                           const half_t* __restrict__ pt_i,
                                           const half_t* __restrict__ lt_i,
                                           const float* __restrict__ wt_i,
                                           float* __restrict__ acc) {
    float x = (gx + 1.0f) * 0.5f * (float)(RESN - 1);
    float y = (gy + 1.0f) * 0.5f * (float)(RESN - 1);
    float l = (gl + 1.0f) * 0.5f * (float)(RESN - 1);
    float x0f = floorf(x), y0f = floorf(y), l0f = floorf(l);
    float wx = x - x0f, wy = y - y0f, wl = l - l0f;
    int x0 = (int)x0f; x0 = max(0, min(x0, RESN - 1));
    int y0 = (int)y0f; y0 = max(0, min(y0, RESN - 1));
    int l0 = (int)l0f; l0 = max(0, min(l0, RESN - 1));
    int x1 = min(x0 + 1, RESN - 1);
    int y1 = min(y0 + 1, RESN - 1);
    int l1 = min(l0 + 1, RESN - 1);
    float w00 = (1.0f - wy) * (1.0f - wx);
    float w01 = (1.0f - wy) * wx;
    float w10 = wy * (1.0f - wx);
    float w11 = wy * wx;
    float wl0 = 1.0f - wl;
    float wl1 = wl;
    const half8* p00 = (const half8*)(pt_i + ((size_t)y0 * RESN + x0) * NCOMP);
    const half8* p01 = (const half8*)(pt_i + ((size_t)y0 * RESN + x1) * NCOMP);
    const half8* p10 = (const half8*)(pt_i + ((size_t)y1 * RESN + x0) * NCOMP);
    const half8* p11 = (const half8*)(pt_i + ((size_t)y1 * RESN + x1) * NCOMP);
    const half8* L0  = (const half8*)(lt_i + (size_t)l0 * NCOMP);
    const half8* L1  = (const half8*)(lt_i + (size_t)l1 * NCOMP);
#pragma unroll 2
    for (int g = 0; g < NCOMP / 8; ++g) {
        half8 a = p00[g], b = p01[g], c = p10[g], d = p11[g];
        half8 e0 = L0[g], e1 = L1[g];
#pragma unroll
        for (int j = 0; j < 8; ++j) {
            float pv = w00 * (float)a[j] + w01 * (float)b[j]
                     + w10 * (float)c[j] + w11 * (float)d[j];
            float lv = wl0 * (float)e0[j] + wl1 * (float)e1[j];
            float pr = pv * lv;
            const float* wrow = wt_i + (size_t)(8 * g + j) * NFEAT;
#pragma unroll
            for (int f = 0; f < NFEAT; ++f)
                acc[f] += pr * wrow[f];
        }
    }
}

__global__ __launch_bounds__(256) void tensor_vm_kernel(
    const float* __restrict__ xyz,
    const half_t* __restrict__ pt,
    const half_t* __restrict__ lt,
    const float* __restrict__ wt,
    float* __restrict__ out) {
    int p = blockIdx.x * blockDim.x + threadIdx.x;
    if (p >= NPTS) return;
    float q0 = xyz[3 * (size_t)p + 0];
    float q1 = xyz[3 * (size_t)p + 1];
    float q2 = xyz[3 * (size_t)p + 2];
    float acc[NFEAT];
#pragma unroll
    for (int f = 0; f < NFEAT; ++f) acc[f] = 0.0f;
    constexpr size_t PSZ = (size_t)RESN * RESN * NCOMP;
    constexpr size_t LSZ = (size_t)RESN * NCOMP;
    constexpr int    WSZ = NCOMP * NFEAT;
    accum_mode(q2, q1, q0, pt,           lt,           wt,           acc);
    accum_mode(q2, q0, q1, pt + PSZ,     lt + LSZ,     wt + WSZ,     acc);
    accum_mode(q1, q0, q2, pt + 2 * PSZ, lt + 2 * LSZ, wt + 2 * WSZ, acc);
    float* o = out + (size_t)p * NFEAT;
#pragma unroll
    for (int f = 0; f < NFEAT; ++f) o[f] = acc[f];
}

__global__ __launch_bounds__(256) void tensor_vm_naive_kernel(
    const float* __restrict__ xyz,
    const float* __restrict__ planes,
    const float* __restrict__ lines,
    const float* __restrict__ W,
    float* __restrict__ out) {
    int p = blockIdx.x * blockDim.x + threadIdx.x;
    if (p >= NPTS) return;
    float q[3];
    q[0] = xyz[3 * (size_t)p + 0];
    q[1] = xyz[3 * (size_t)p + 1];
    q[2] = xyz[3 * (size_t)p + 2];
    float acc[NFEAT];
    for (int f = 0; f < NFEAT; ++f) acc[f] = 0.0f;
    const int AX[3] = {2, 2, 1};
    const int BX[3] = {1, 0, 0};
    for (int i = 0; i < 3; ++i) {
        float gx = q[AX[i]], gy = q[BX[i]], gl = q[i];
        float x = (gx + 1.0f) * 0.5f * (float)(RESN - 1);
        float y = (gy + 1.0f) * 0.5f * (float)(RESN - 1);
        float l = (gl + 1.0f) * 0.5f * (float)(RESN - 1);
        float x0f = floorf(x), y0f = floorf(y), l0f = floorf(l);
        float wx = x - x0f, wy = y - y0f, wl = l - l0f;
        int x0 = max(0, min((int)x0f, RESN - 1));
        int y0 = max(0, min((int)y0f, RESN - 1));
        int l0 = max(0, min((int)l0f, RESN - 1));
        int x1 = min(x0 + 1, RESN - 1);
        int y1 = min(y0 + 1, RESN - 1);
        int l1 = min(l0 + 1, RESN - 1);
        float w00 = (1.0f - wy) * (1.0f - wx);
        float w01 = (1.0f - wy) * wx;
        float w10 = wy * (1.0f - wx);
        float w11 = wy * wx;
        const float* pl = planes + (size_t)i * NCOMP * RESN * RESN;
        const float* ln = lines + (size_t)i * NCOMP * RESN;
        for (int c = 0; c < NCOMP; ++c) {
            const float* plc = pl + (size_t)c * RESN * RESN;
            float v00 = plc[(size_t)y0 * RESN + x0];
            float v01 = plc[(size_t)y0 * RESN + x1];
            float v10 = plc[(size_t)y1 * RESN + x0];
            float v11 = plc[(size_t)y1 * RESN + x1];
            float pv = w00 * v00 + w01 * v01 + w10 * v10 + w11 * v11;
            float lv = (1.0f - wl) * ln[(size_t)c * RESN + l0] + wl * ln[(size_t)c * RESN + l1];
            float pr = pv * lv;
            int cc = i * NCOMP + c;
            for (int f = 0; f < NFEAT; ++f)
                acc[f] += pr * W[(size_t)f * CCTOT + cc];
        }
    }
    float* o = out + (size_t)p * NFEAT;
    for (int f = 0; f < NFEAT; ++f) o[f] = acc[f];
}

}  // namespace

extern "C" void kernel_launch(void* const* d_in, const int* in_sizes, int n_in,
                              void* d_out, int out_size, void* d_ws, size_t ws_size,
                              hipStream_t stream) {
    (void)in_sizes; (void)n_in; (void)out_size;
    const float* xyz    = (const float*)d_in[0];
    const float* planes = (const float*)d_in[1];
    const float* lines  = (const float*)d_in[2];
    const float* W      = (const float*)d_in[3];
    float* out = (float*)d_out;

    constexpr size_t PT_HALVES   = (size_t)3 * RESN * RESN * NCOMP;  // 12,960,000
    constexpr size_t LT_HALVES   = (size_t)3 * RESN * NCOMP;         // 43,200
    constexpr size_t WT_FLOATS   = (size_t)CCTOT * NFEAT;            // 3,888

    // ws layout: [wt fp32][wfrag bf16][pt fp16][lt fp16][hist][start][xyzs]
    constexpr size_t WT_BYTES    = WT_FLOATS * sizeof(float);        // 15,552
    constexpr size_t WFRAG_BYTES = (size_t)WFRAG_TOT * 2;            // 12,288
    constexpr size_t PT_BYTES    = PT_HALVES * sizeof(half_t);       // 25,920,000
    constexpr size_t LT_BYTES    = LT_HALVES * sizeof(half_t);       // 86,400
    constexpr size_t HIST_BYTES  = (size_t)NBUCKET * sizeof(int);    // 131,072
    constexpr size_t XYZS_BYTES  = (size_t)NPTS * sizeof(float4);    // 16,000,000
    constexpr size_t NEED_PLAIN  = WT_BYTES + WFRAG_BYTES + PT_BYTES + LT_BYTES;
    constexpr size_t NEED_SORT   = NEED_PLAIN + 2 * HIST_BYTES + XYZS_BYTES;

    if (ws_size >= NEED_PLAIN) {
        float*          wt    = (float*)d_ws;
        unsigned short* wfrag = (unsigned short*)((char*)d_ws + WT_BYTES);
        half_t*         pt    = (half_t*)((char*)d_ws + WT_BYTES + WFRAG_BYTES);
        half_t*         lt    = (half_t*)((char*)d_ws + WT_BYTES + WFRAG_BYTES + PT_BYTES);
        if (ws_size >= NEED_SORT) {
            int*    hist  = (int*)((char*)d_ws + NEED_PLAIN);
            int*    start = (int*)((char*)d_ws + NEED_PLAIN + HIST_BYTES);
            float4* xyzs  = (float4*)((char*)d_ws + NEED_PLAIN + 2 * HIST_BYTES);
            hipMemsetAsync(hist, 0, HIST_BYTES, stream);
            fused_front_k<<<TP_BLOCKS + SU_BLOCKS + HB_BLOCKS, 256, 0, stream>>>(
                planes, lines, W, xyz, pt, lt, wt, wfrag, hist);
            scan_k<<<1, 1024, 0, stream>>>(hist, start);
            scatter_k<<<(NPTS + 255) / 256, 256, 0, stream>>>(xyz, start, xyzs);
            tensor_vm_mfma_kernel<<<MAIN_NWG, MAIN_BLK, 0, stream>>>(
                xyzs, pt, lt, wfrag, out);
        } else {
            fused_front_k<<<TP_BLOCKS + SU_BLOCKS, 256, 0, stream>>>(
                planes, lines, W, xyz, pt, lt, wt, wfrag, nullptr);
            tensor_vm_kernel<<<(NPTS + 255) / 256, 256, 0, stream>>>(xyz, pt, lt, wt, out);
        }
    } else {
        tensor_vm_naive_kernel<<<(NPTS + 255) / 256, 256, 0, stream>>>(xyz, planes, lines, W, out);
    }
}

// Round 6
// 446.384 us; speedup vs baseline: 1.1017x; 1.0246x over previous
//
#include <hip/hip_runtime.h>

namespace {

constexpr int NCOMP = 48;
constexpr int RESN  = 300;
constexpr int NFEAT = 27;
constexpr int NPTS  = 1000000;
constexpr int CCTOT = 3 * NCOMP;   // 144
constexpr int GRID1 = 32;          // sort cells per axis
constexpr int NBUCKET = GRID1 * GRID1 * GRID1;  // 32768

typedef _Float16 half_t;
typedef __attribute__((ext_vector_type(8))) _Float16 half8;
typedef __attribute__((ext_vector_type(8))) short          short8;   // 8 bf16 (4 VGPRs)
typedef __attribute__((ext_vector_type(8))) unsigned short ushort8;
typedef __attribute__((ext_vector_type(4))) float          floatx4;

// f32 -> bf16 round-to-nearest-even
__device__ __forceinline__ unsigned short f32_to_bf16(float x) {
    unsigned u = __float_as_uint(x);
    u += 0x7fffu + ((u >> 16) & 1u);
    return (unsigned short)(u >> 16);
}

// LDS row stride: 56 bf16 = 112 B (16B-aligned). No K-pad needed: the
// B-fragments (wfrag) are zero for k>=48, and lanes with q>=2 take a
// register-zero ahi, so the k in [48,64) region never contributes.
constexpr int SH_STRIDE = 56;

// ---------------- fused front-end kernel ----------------
// Block ranges (all independent work; hist[] is pre-zeroed by a memset node):
//   [0, TP_BLOCKS)                planes (3,48,300,300) fp32 -> (3,300,300,48) fp16
//   [TP_BLOCKS, +SU_BLOCKS)       lines transpose + Wt + W MFMA B-fragments
//   [TP_BLOCKS+SU_BLOCKS, +HB)    histogram of xyz cell keys (atomics)
constexpr int TP_TOTAL  = 3 * RESN * RESN;          // 270000
constexpr int TP_BLOCKS = (TP_TOTAL + 255) / 256;   // 1055
constexpr int LINES_TOT = 3 * RESN;                 // 900
constexpr int WT_TOT    = NFEAT * CCTOT;            // 3888
constexpr int WFRAG_TOT = 3 * 2 * 2 * 64 * 8;       // 6144
constexpr int SU_TOTAL  = LINES_TOT + WT_TOT + WFRAG_TOT;  // 10932
constexpr int SU_BLOCKS = (SU_TOTAL + 255) / 256;   // 43
constexpr int HB_BLOCKS = (NPTS + 255) / 256;       // 3907

__device__ __forceinline__ int cell_of(float q) {
    float t = (q + 1.0f) * (0.5f * (float)GRID1);   // [0,32)
    int c = (int)t;
    return min(max(c, 0), GRID1 - 1);
}
__device__ __forceinline__ int key_of(float q0, float q1, float q2) {
    return (cell_of(q0) * GRID1 + cell_of(q1)) * GRID1 + cell_of(q2);
}

__global__ __launch_bounds__(256) void fused_front_k(
    const float* __restrict__ planes, const float* __restrict__ lines,
    const float* __restrict__ W, const float* __restrict__ xyz,
    half_t* __restrict__ pt, half_t* __restrict__ lt,
    float* __restrict__ wt, unsigned short* __restrict__ wfrag,
    int* __restrict__ hist) {
    int b = blockIdx.x;
    if (b < TP_BLOCKS) {
        int idx = b * 256 + threadIdx.x;
        if (idx >= TP_TOTAL) return;
        int i   = idx / (RESN * RESN);
        int rem = idx - i * (RESN * RESN);          // y*RESN + x
        const float* s = planes + (size_t)i * NCOMP * RESN * RESN + rem;
        half8* d = (half8*)(pt + (size_t)idx * NCOMP);
#pragma unroll
        for (int g = 0; g < NCOMP / 8; ++g) {
            half8 h;
#pragma unroll
            for (int k = 0; k < 8; ++k)
                h[k] = (half_t)s[(size_t)(g * 8 + k) * (RESN * RESN)];  // coalesced across lanes
            d[g] = h;
        }
        return;
    }
    if (b < TP_BLOCKS + SU_BLOCKS) {
        int idx = (b - TP_BLOCKS) * 256 + threadIdx.x;
        if (idx < LINES_TOT) {
            int i = idx / RESN;
            int y = idx - i * RESN;
            const float* s = lines + (size_t)i * NCOMP * RESN + y;
            half8* d = (half8*)(lt + (size_t)idx * NCOMP);
#pragma unroll
            for (int g = 0; g < NCOMP / 8; ++g) {
                half8 h;
#pragma unroll
                for (int k = 0; k < 8; ++k)
                    h[k] = (half_t)s[(size_t)(g * 8 + k) * RESN];
                d[g] = h;
            }
            return;
        }
        idx -= LINES_TOT;
        if (idx < WT_TOT) {
            int f  = idx / CCTOT;
            int cc = idx - f * CCTOT;
            wt[(size_t)cc * NFEAT + f] = W[idx];
            return;
        }
        idx -= WT_TOT;
        if (idx < WFRAG_TOT) {
            // [mode][kblk:2][n:2][lane:64][j:8]; value = W[f][mode*48 + kblk*32 + 8*(lane>>4)+j]
            int j    = idx & 7;
            int lane = (idx >> 3) & 63;
            int nn   = (idx >> 9) & 1;
            int kb   = (idx >> 10) & 1;
            int md   = idx >> 11;
            int f  = nn * 16 + (lane & 15);
            int kk = kb * 32 + ((lane >> 4) << 3) + j;
            float vf = 0.0f;
            if (f < NFEAT && kk < NCOMP)
                vf = W[(size_t)f * CCTOT + md * NCOMP + kk];
            wfrag[idx] = f32_to_bf16(vf);
        }
        return;
    }
    // histogram
    int p = (b - TP_BLOCKS - SU_BLOCKS) * 256 + threadIdx.x;
    if (p >= NPTS || !hist) return;
    float q0 = xyz[3 * (size_t)p + 0];
    float q1 = xyz[3 * (size_t)p + 1];
    float q2 = xyz[3 * (size_t)p + 2];
    atomicAdd(&hist[key_of(q0, q1, q2)], 1);
}

// ---------------- counting sort: scan + scatter ----------------

__global__ __launch_bounds__(1024) void scan_k(const int* __restrict__ hist,
                                               int* __restrict__ start) {
    __shared__ int part[1024];
    int t = threadIdx.x;
    int base = t * (NBUCKET / 1024);
    int s = 0;
#pragma unroll 4
    for (int j = 0; j < NBUCKET / 1024; ++j) s += hist[base + j];
    part[t] = s;
    __syncthreads();
    for (int off = 1; off < 1024; off <<= 1) {
        int v = (t >= off) ? part[t - off] : 0;
        __syncthreads();
        part[t] += v;
        __syncthreads();
    }
    int run = (t == 0) ? 0 : part[t - 1];
    for (int j = 0; j < NBUCKET / 1024; ++j) {
        start[base + j] = run;
        run += hist[base + j];
    }
}

__global__ __launch_bounds__(256) void scatter_k(const float* __restrict__ xyz,
                                                 int* __restrict__ start,
                                                 float4* __restrict__ xyzs) {
    int p = blockIdx.x * blockDim.x + threadIdx.x;
    if (p >= NPTS) return;
    float q0 = xyz[3 * (size_t)p + 0];
    float q1 = xyz[3 * (size_t)p + 1];
    float q2 = xyz[3 * (size_t)p + 2];
    int slot = atomicAdd(&start[key_of(q0, q1, q2)], 1);
    float4 v;
    v.x = q0; v.y = q1; v.z = q2; v.w = __int_as_float(p);
    xyzs[slot] = v;
}

// ---------------- MFMA main kernel ----------------

// interpolate one mode for this lane's point; write 48 bf16 products to its LDS row
__device__ __forceinline__ void produce_mode(float gx, float gy, float gl,
                                             const half_t* __restrict__ pt_i,
                                             const half_t* __restrict__ lt_i,
                                             unsigned short* __restrict__ shrow) {
    float x = (gx + 1.0f) * 0.5f * (float)(RESN - 1);
    float y = (gy + 1.0f) * 0.5f * (float)(RESN - 1);
    float l = (gl + 1.0f) * 0.5f * (float)(RESN - 1);
    float x0f = floorf(x), y0f = floorf(y), l0f = floorf(l);
    float wx = x - x0f, wy = y - y0f, wl = l - l0f;
    int x0 = max(0, min((int)x0f, RESN - 1));
    int y0 = max(0, min((int)y0f, RESN - 1));
    int l0 = max(0, min((int)l0f, RESN - 1));
    int x1 = min(x0 + 1, RESN - 1);
    int y1 = min(y0 + 1, RESN - 1);
    int l1 = min(l0 + 1, RESN - 1);
    float w00 = (1.0f - wy) * (1.0f - wx);
    float w01 = (1.0f - wy) * wx;
    float w10 = wy * (1.0f - wx);
    float w11 = wy * wx;
    float wl0 = 1.0f - wl;
    float wl1 = wl;

    const half8* p00 = (const half8*)(pt_i + ((size_t)y0 * RESN + x0) * NCOMP);
    const half8* p01 = (const half8*)(pt_i + ((size_t)y0 * RESN + x1) * NCOMP);
    const half8* p10 = (const half8*)(pt_i + ((size_t)y1 * RESN + x0) * NCOMP);
    const half8* p11 = (const half8*)(pt_i + ((size_t)y1 * RESN + x1) * NCOMP);
    const half8* L0  = (const half8*)(lt_i + (size_t)l0 * NCOMP);
    const half8* L1  = (const half8*)(lt_i + (size_t)l1 * NCOMP);

#pragma unroll 2
    for (int g = 0; g < NCOMP / 8; ++g) {
        half8 a = p00[g], b = p01[g], c = p10[g], d = p11[g];
        half8 e0 = L0[g], e1 = L1[g];
        ushort8 h;
#pragma unroll
        for (int j = 0; j < 8; ++j) {
            float pv = w00 * (float)a[j] + w01 * (float)b[j]
                     + w10 * (float)c[j] + w11 * (float)d[j];
            float lv = wl0 * (float)e0[j] + wl1 * (float)e1[j];
            h[j] = f32_to_bf16(pv * lv);
        }
        *(ushort8*)(shrow + g * 8) = h;
    }
}

// one mode's worth of MFMAs over the wave's 64-point LDS tile.
// K=48 done as two 16x16x32_bf16: k[0,32) real; k[32,48) real for lanes q<2,
// register-zero for q>=2 (B is also zero there — k>=48 contributes nothing).
__device__ __forceinline__ void mfma_phase(const unsigned short* __restrict__ shw,
                                           int r, int q,
                                           short8 blo0, short8 blo1,
                                           short8 bhi0, short8 bhi1,
                                           floatx4 acc[4][2]) {
    const short8 z8 = {0, 0, 0, 0, 0, 0, 0, 0};
#pragma unroll
    for (int m = 0; m < 4; ++m) {
        const unsigned short* rb = shw + (size_t)(m * 16 + r) * SH_STRIDE;
        short8 alo = *(const short8*)(rb + q * 8);                 // k 8q..8q+7 blocks -> 0..31
        short8 ahl = *(const short8*)(rb + 32 + (q & 1) * 8);      // k 32..47 (addr clamped)
        short8 ahi = (q < 2) ? ahl : z8;                           // q>=2 -> zero (no NaN*0)
        acc[m][0] = __builtin_amdgcn_mfma_f32_16x16x32_bf16(alo, blo0, acc[m][0], 0, 0, 0);
        acc[m][0] = __builtin_amdgcn_mfma_f32_16x16x32_bf16(ahi, bhi0, acc[m][0], 0, 0, 0);
        acc[m][1] = __builtin_amdgcn_mfma_f32_16x16x32_bf16(alo, blo1, acc[m][1], 0, 0, 0);
        acc[m][1] = __builtin_amdgcn_mfma_f32_16x16x32_bf16(ahi, bhi1, acc[m][1], 0, 0, 0);
    }
}

// 128-thread blocks, 2 waves, fully decoupled (no __syncthreads): each wave
// owns its sh[w] tile; wave-synchronous LDS via s_waitcnt lgkmcnt(0).
constexpr int MAIN_BLK = 128;
constexpr int MAIN_NWG = (NPTS + MAIN_BLK - 1) / MAIN_BLK;   // 7813

// bijective XCD-chunked swizzle (m204): consecutive data chunks land on one XCD
// so sorted neighbors share plane rows in that XCD's 4MB L2.
__device__ __forceinline__ int swz_main(int orig) {
    constexpr int Q = MAIN_NWG / 8, R = MAIN_NWG % 8;   // 976, 5
    int x = orig & 7, p = orig >> 3;
    return (x < R ? x * (Q + 1) : R * (Q + 1) + (x - R) * Q) + p;
}

__global__ __launch_bounds__(MAIN_BLK) void tensor_vm_mfma_kernel(
    const float4* __restrict__ xyzs,
    const half_t* __restrict__ pt,
    const half_t* __restrict__ lt,
    const unsigned short* __restrict__ wfrag,
    float* __restrict__ out) {
    __shared__ unsigned short sh[2][64][SH_STRIDE];   // per-wave product tiles, 14 KB

    const int bid = swz_main(blockIdx.x);
    const int tid = threadIdx.x;
    const int w  = tid >> 6;
    const int ln = tid & 63;
    const int r  = ln & 15;
    const int q  = ln >> 4;
    const int gidx = bid * MAIN_BLK + tid;
    const int i = min(gidx, NPTS - 1);        // clamp (writes guarded below)
    float4 v = xyzs[i];
    const float q0 = v.x, q1 = v.y, q2 = v.z;
    const int permInt = __float_as_int(v.w);

    floatx4 acc[4][2];
    const floatx4 z = {0.f, 0.f, 0.f, 0.f};
#pragma unroll
    for (int m = 0; m < 4; ++m) { acc[m][0] = z; acc[m][1] = z; }

    constexpr size_t PSZ = (size_t)RESN * RESN * NCOMP;
    constexpr size_t LSZ = (size_t)RESN * NCOMP;

    unsigned short* shrow = &sh[w][ln][0];
    const unsigned short* shw = &sh[w][0][0];

    // PLANE_AX = ((2,1),(2,0),(1,0)); line axis = mode index
    const float gxs[3] = {q2, q2, q1};
    const float gys[3] = {q1, q0, q0};
    const float gls[3] = {q0, q1, q2};

#pragma unroll
    for (int md = 0; md < 3; ++md) {
        // B-fragments for this mode (L2-hot 12 KB), issue early
        const unsigned short* wfb = wfrag + (size_t)md * 2048 + (size_t)ln * 8;
        short8 blo0 = *(const short8*)(wfb);           // kblk=0, n=0
        short8 blo1 = *(const short8*)(wfb + 512);     // kblk=0, n=1
        short8 bhi0 = *(const short8*)(wfb + 1024);    // kblk=1, n=0
        short8 bhi1 = *(const short8*)(wfb + 1536);    // kblk=1, n=1

        produce_mode(gxs[md], gys[md], gls[md], pt + md * PSZ, lt + md * LSZ, shrow);
        // wave-synchronous: this wave's LDS writes complete before its reads.
        asm volatile("s_waitcnt lgkmcnt(0)" ::: "memory");
        __builtin_amdgcn_sched_barrier(0);
        mfma_phase(shw, r, q, blo0, blo1, bhi0, bhi1, acc);
        __builtin_amdgcn_sched_barrier(0);   // keep next produce's stores below the reads
    }

    // epilogue: D layout col=lane&15 (feature), row=(lane>>4)*4+reg (point)
    const int blockBase = bid * MAIN_BLK + w * 64;
#pragma unroll
    for (int m = 0; m < 4; ++m) {
#pragma unroll
        for (int rr = 0; rr < 4; ++rr) {
            const int pl = m * 16 + q * 4 + rr;
            const int pp = __shfl(permInt, pl);
            if (blockBase + pl < NPTS) {
                float* o = out + (size_t)pp * NFEAT + r;
                o[0] = acc[m][0][rr];
                if (r < NFEAT - 16) o[16] = acc[m][1][rr];
            }
        }
    }
}

// ---------------- scalar fallbacks ----------------

__device__ __forceinline__ void accum_mode(float gx, float gy, float gl,
                                           const half_t* __restrict__ pt_i,
                                           const half_t* __restrict__ lt_i,
                                           const float* __restrict__ wt_i,
                                           float* __restrict__ acc) {
    float x = (gx + 1.0f) * 0.5f * (float)(RESN - 1);
    float y = (gy + 1.0f) * 0.5f * (float)(RESN - 1);
    float l = (gl + 1.0f) * 0.5f * (float)(RESN - 1);
    float x0f = floorf(x), y0f = floorf(y), l0f = floorf(l);
    float wx = x - x0f, wy = y - y0f, wl = l - l0f;
    int x0 = (int)x0f; x0 = max(0, min(x0, RESN - 1));
    int y0 = (int)y0f; y0 = max(0, min(y0, RESN - 1));
    int l0 = (int)l0f; l0 = max(0, min(l0, RESN - 1));
    int x1 = min(x0 + 1, RESN - 1);
    int y1 = min(y0 + 1, RESN - 1);
    int l1 = min(l0 + 1, RESN - 1);
    float w00 = (1.0f - wy) * (1.0f - wx);
    float w01 = (1.0f - wy) * wx;
    float w10 = wy * (1.0f - wx);
    float w11 = wy * wx;
    float wl0 = 1.0f - wl;
    float wl1 = wl;
    const half8* p00 = (const half8*)(pt_i + ((size_t)y0 * RESN + x0) * NCOMP);
    const half8* p01 = (const half8*)(pt_i + ((size_t)y0 * RESN + x1) * NCOMP);
    const half8* p10 = (const half8*)(pt_i + ((size_t)y1 * RESN + x0) * NCOMP);
    const half8* p11 = (const half8*)(pt_i + ((size_t)y1 * RESN + x1) * NCOMP);
    const half8* L0  = (const half8*)(lt_i + (size_t)l0 * NCOMP);
    const half8* L1  = (const half8*)(lt_i + (size_t)l1 * NCOMP);
#pragma unroll 2
    for (int g = 0; g < NCOMP / 8; ++g) {
        half8 a = p00[g], b = p01[g], c = p10[g], d = p11[g];
        half8 e0 = L0[g], e1 = L1[g];
#pragma unroll
        for (int j = 0; j < 8; ++j) {
            float pv = w00 * (float)a[j] + w01 * (float)b[j]
                     + w10 * (float)c[j] + w11 * (float)d[j];
            float lv = wl0 * (float)e0[j] + wl1 * (float)e1[j];
            float pr = pv * lv;
            const float* wrow = wt_i + (size_t)(8 * g + j) * NFEAT;
#pragma unroll
            for (int f = 0; f < NFEAT; ++f)
                acc[f] += pr * wrow[f];
        }
    }
}

__global__ __launch_bounds__(256) void tensor_vm_kernel(
    const float* __restrict__ xyz,
    const half_t* __restrict__ pt,
    const half_t* __restrict__ lt,
    const float* __restrict__ wt,
    float* __restrict__ out) {
    int p = blockIdx.x * blockDim.x + threadIdx.x;
    if (p >= NPTS) return;
    float q0 = xyz[3 * (size_t)p + 0];
    float q1 = xyz[3 * (size_t)p + 1];
    float q2 = xyz[3 * (size_t)p + 2];
    float acc[NFEAT];
#pragma unroll
    for (int f = 0; f < NFEAT; ++f) acc[f] = 0.0f;
    constexpr size_t PSZ = (size_t)RESN * RESN * NCOMP;
    constexpr size_t LSZ = (size_t)RESN * NCOMP;
    constexpr int    WSZ = NCOMP * NFEAT;
    accum_mode(q2, q1, q0, pt,           lt,           wt,           acc);
    accum_mode(q2, q0, q1, pt + PSZ,     lt + LSZ,     wt + WSZ,     acc);
    accum_mode(q1, q0, q2, pt + 2 * PSZ, lt + 2 * LSZ, wt + 2 * WSZ, acc);
    float* o = out + (size_t)p * NFEAT;
#pragma unroll
    for (int f = 0; f < NFEAT; ++f) o[f] = acc[f];
}

__global__ __launch_bounds__(256) void tensor_vm_naive_kernel(
    const float* __restrict__ xyz,
    const float* __restrict__ planes,
    const float* __restrict__ lines,
    const float* __restrict__ W,
    float* __restrict__ out) {
    int p = blockIdx.x * blockDim.x + threadIdx.x;
    if (p >= NPTS) return;
    float q[3];
    q[0] = xyz[3 * (size_t)p + 0];
    q[1] = xyz[3 * (size_t)p + 1];
    q[2] = xyz[3 * (size_t)p + 2];
    float acc[NFEAT];
    for (int f = 0; f < NFEAT; ++f) acc[f] = 0.0f;
    const int AX[3] = {2, 2, 1};
    const int BX[3] = {1, 0, 0};
    for (int i = 0; i < 3; ++i) {
        float gx = q[AX[i]], gy = q[BX[i]], gl = q[i];
        float x = (gx + 1.0f) * 0.5f * (float)(RESN - 1);
        float y = (gy + 1.0f) * 0.5f * (float)(RESN - 1);
        float l = (gl + 1.0f) * 0.5f * (float)(RESN - 1);
        float x0f = floorf(x), y0f = floorf(y), l0f = floorf(l);
        float wx = x - x0f, wy = y - y0f, wl = l - l0f;
        int x0 = max(0, min((int)x0f, RESN - 1));
        int y0 = max(0, min((int)y0f, RESN - 1));
        int l0 = max(0, min((int)l0f, RESN - 1));
        int x1 = min(x0 + 1, RESN - 1);
        int y1 = min(y0 + 1, RESN - 1);
        int l1 = min(l0 + 1, RESN - 1);
        float w00 = (1.0f - wy) * (1.0f - wx);
        float w01 = (1.0f - wy) * wx;
        float w10 = wy * (1.0f - wx);
        float w11 = wy * wx;
        const float* pl = planes + (size_t)i * NCOMP * RESN * RESN;
        const float* ln = lines + (size_t)i * NCOMP * RESN;
        for (int c = 0; c < NCOMP; ++c) {
            const float* plc = pl + (size_t)c * RESN * RESN;
            float v00 = plc[(size_t)y0 * RESN + x0];
            float v01 = plc[(size_t)y0 * RESN + x1];
            float v10 = plc[(size_t)y1 * RESN + x0];
            float v11 = plc[(size_t)y1 * RESN + x1];
            float pv = w00 * v00 + w01 * v01 + w10 * v10 + w11 * v11;
            float lv = (1.0f - wl) * ln[(size_t)c * RESN + l0] + wl * ln[(size_t)c * RESN + l1];
            float pr = pv * lv;
            int cc = i * NCOMP + c;
            for (int f = 0; f < NFEAT; ++f)
                acc[f] += pr * W[(size_t)f * CCTOT + cc];
        }
    }
    float* o = out + (size_t)p * NFEAT;
    for (int f = 0; f < NFEAT; ++f) o[f] = acc[f];
}

}  // namespace

extern "C" void kernel_launch(void* const* d_in, const int* in_sizes, int n_in,
                              void* d_out, int out_size, void* d_ws, size_t ws_size,
                              hipStream_t stream) {
    (void)in_sizes; (void)n_in; (void)out_size;
    const float* xyz    = (const float*)d_in[0];
    const float* planes = (const float*)d_in[1];
    const float* lines  = (const float*)d_in[2];
    const float* W      = (const float*)d_in[3];
    float* out = (float*)d_out;

    constexpr size_t PT_HALVES   = (size_t)3 * RESN * RESN * NCOMP;  // 12,960,000
    constexpr size_t LT_HALVES   = (size_t)3 * RESN * NCOMP;         // 43,200
    constexpr size_t WT_FLOATS   = (size_t)CCTOT * NFEAT;            // 3,888

    // ws layout: [wt fp32][wfrag bf16][pt fp16][lt fp16][hist][start][xyzs]
    constexpr size_t WT_BYTES    = WT_FLOATS * sizeof(float);        // 15,552
    constexpr size_t WFRAG_BYTES = (size_t)WFRAG_TOT * 2;            // 12,288
    constexpr size_t PT_BYTES    = PT_HALVES * sizeof(half_t);       // 25,920,000
    constexpr size_t LT_BYTES    = LT_HALVES * sizeof(half_t);       // 86,400
    constexpr size_t HIST_BYTES  = (size_t)NBUCKET * sizeof(int);    // 131,072
    constexpr size_t XYZS_BYTES  = (size_t)NPTS * sizeof(float4);    // 16,000,000
    constexpr size_t NEED_PLAIN  = WT_BYTES + WFRAG_BYTES + PT_BYTES + LT_BYTES;
    constexpr size_t NEED_SORT   = NEED_PLAIN + 2 * HIST_BYTES + XYZS_BYTES;

    if (ws_size >= NEED_PLAIN) {
        float*          wt    = (float*)d_ws;
        unsigned short* wfrag = (unsigned short*)((char*)d_ws + WT_BYTES);
        half_t*         pt    = (half_t*)((char*)d_ws + WT_BYTES + WFRAG_BYTES);
        half_t*         lt    = (half_t*)((char*)d_ws + WT_BYTES + WFRAG_BYTES + PT_BYTES);
        if (ws_size >= NEED_SORT) {
            int*    hist  = (int*)((char*)d_ws + NEED_PLAIN);
            int*    start = (int*)((char*)d_ws + NEED_PLAIN + HIST_BYTES);
            float4* xyzs  = (float4*)((char*)d_ws + NEED_PLAIN + 2 * HIST_BYTES);
            hipMemsetAsync(hist, 0, HIST_BYTES, stream);
            fused_front_k<<<TP_BLOCKS + SU_BLOCKS + HB_BLOCKS, 256, 0, stream>>>(
                planes, lines, W, xyz, pt, lt, wt, wfrag, hist);
            scan_k<<<1, 1024, 0, stream>>>(hist, start);
            scatter_k<<<(NPTS + 255) / 256, 256, 0, stream>>>(xyz, start, xyzs);
            tensor_vm_mfma_kernel<<<MAIN_NWG, MAIN_BLK, 0, stream>>>(
                xyzs, pt, lt, wfrag, out);
        } else {
            fused_front_k<<<TP_BLOCKS + SU_BLOCKS, 256, 0, stream>>>(
                planes, lines, W, xyz, pt, lt, wt, wfrag, nullptr);
            tensor_vm_kernel<<<(NPTS + 255) / 256, 256, 0, stream>>>(xyz, pt, lt, wt, out);
        }
    } else {
        tensor_vm_naive_kernel<<<(NPTS + 255) / 256, 256, 0, stream>>>(xyz, planes, lines, W, out);
    }
}

// Round 7
// 402.400 us; speedup vs baseline: 1.2222x; 1.1093x over previous
//
#include <hip/hip_runtime.h>

namespace {

constexpr int NCOMP = 48;
constexpr int RESN  = 300;
constexpr int NFEAT = 27;
constexpr int NPTS  = 1000000;
constexpr int CCTOT = 3 * NCOMP;   // 144
constexpr int GRID1 = 32;          // sort cells per axis
constexpr int NBUCKET = GRID1 * GRID1 * GRID1;  // 32768

typedef _Float16 half_t;
typedef __attribute__((ext_vector_type(8))) _Float16 half8;
typedef __attribute__((ext_vector_type(8))) short          short8;   // 8 bf16 (4 VGPRs)
typedef __attribute__((ext_vector_type(8))) unsigned short ushort8;
typedef __attribute__((ext_vector_type(4))) float          floatx4;

// f32 -> bf16 round-to-nearest-even
__device__ __forceinline__ unsigned short f32_to_bf16(float x) {
    unsigned u = __float_as_uint(x);
    u += 0x7fffu + ((u >> 16) & 1u);
    return (unsigned short)(u >> 16);
}

// LDS row stride of the MFMA A-tile: 56 bf16 = 112 B (16B-aligned).
constexpr int SH_STRIDE = 56;

// lt gets a 64-half zeroed pad so the l0=299 (+96B) read is safe finite data.
constexpr int LT_PAD = 64;

// ---------------- fused front-end kernel ----------------
//   [0, TP_BLOCKS)                planes (3,48,300,300) fp32 -> (3,300,300,48) fp16
//   [TP_BLOCKS, +SU_BLOCKS)       lines transpose + Wt + W MFMA B-fragments + lt pad zero
//   [TP_BLOCKS+SU_BLOCKS, +HB)    histogram of xyz cell keys (atomics)
constexpr int TP_TOTAL  = 3 * RESN * RESN;          // 270000
constexpr int TP_BLOCKS = (TP_TOTAL + 255) / 256;   // 1055
constexpr int LINES_TOT = 3 * RESN;                 // 900
constexpr int WT_TOT    = NFEAT * CCTOT;            // 3888
constexpr int WFRAG_TOT = 3 * 2 * 2 * 64 * 8;       // 6144
constexpr int SU_TOTAL  = LINES_TOT + WT_TOT + WFRAG_TOT + LT_PAD;  // 10996
constexpr int SU_BLOCKS = (SU_TOTAL + 255) / 256;   // 43
constexpr int HB_BLOCKS = (NPTS + 255) / 256;       // 3907

__device__ __forceinline__ int cell_of(float q) {
    float t = (q + 1.0f) * (0.5f * (float)GRID1);   // [0,32)
    int c = (int)t;
    return min(max(c, 0), GRID1 - 1);
}
__device__ __forceinline__ int key_of(float q0, float q1, float q2) {
    return (cell_of(q0) * GRID1 + cell_of(q1)) * GRID1 + cell_of(q2);
}

__global__ __launch_bounds__(256) void fused_front_k(
    const float* __restrict__ planes, const float* __restrict__ lines,
    const float* __restrict__ W, const float* __restrict__ xyz,
    half_t* __restrict__ pt, half_t* __restrict__ lt,
    float* __restrict__ wt, unsigned short* __restrict__ wfrag,
    int* __restrict__ hist) {
    int b = blockIdx.x;
    if (b < TP_BLOCKS) {
        int idx = b * 256 + threadIdx.x;
        if (idx >= TP_TOTAL) return;
        int i   = idx / (RESN * RESN);
        int rem = idx - i * (RESN * RESN);          // y*RESN + x
        const float* s = planes + (size_t)i * NCOMP * RESN * RESN + rem;
        half8* d = (half8*)(pt + (size_t)idx * NCOMP);
#pragma unroll
        for (int g = 0; g < NCOMP / 8; ++g) {
            half8 h;
#pragma unroll
            for (int k = 0; k < 8; ++k)
                h[k] = (half_t)s[(size_t)(g * 8 + k) * (RESN * RESN)];  // coalesced across lanes
            d[g] = h;
        }
        return;
    }
    if (b < TP_BLOCKS + SU_BLOCKS) {
        int idx = (b - TP_BLOCKS) * 256 + threadIdx.x;
        if (idx < LINES_TOT) {
            int i = idx / RESN;
            int y = idx - i * RESN;
            const float* s = lines + (size_t)i * NCOMP * RESN + y;
            half8* d = (half8*)(lt + (size_t)idx * NCOMP);
#pragma unroll
            for (int g = 0; g < NCOMP / 8; ++g) {
                half8 h;
#pragma unroll
                for (int k = 0; k < 8; ++k)
                    h[k] = (half_t)s[(size_t)(g * 8 + k) * RESN];
                d[g] = h;
            }
            return;
        }
        idx -= LINES_TOT;
        if (idx < WT_TOT) {
            int f  = idx / CCTOT;
            int cc = idx - f * CCTOT;
            wt[(size_t)cc * NFEAT + f] = W[idx];
            return;
        }
        idx -= WT_TOT;
        if (idx < WFRAG_TOT) {
            // [mode][kblk:2][n:2][lane:64][j:8]; value = W[f][mode*48 + kblk*32 + 8*(lane>>4)+j]
            int j    = idx & 7;
            int lane = (idx >> 3) & 63;
            int nn   = (idx >> 9) & 1;
            int kb   = (idx >> 10) & 1;
            int md   = idx >> 11;
            int f  = nn * 16 + (lane & 15);
            int kk = kb * 32 + ((lane >> 4) << 3) + j;
            float vf = 0.0f;
            if (f < NFEAT && kk < NCOMP)
                vf = W[(size_t)f * CCTOT + md * NCOMP + kk];
            wfrag[idx] = f32_to_bf16(vf);
            return;
        }
        idx -= WFRAG_TOT;
        if (idx < LT_PAD) lt[(size_t)3 * RESN * NCOMP + idx] = (half_t)0.f;
        return;
    }
    // histogram
    int p = (b - TP_BLOCKS - SU_BLOCKS) * 256 + threadIdx.x;
    if (p >= NPTS || !hist) return;
    float q0 = xyz[3 * (size_t)p + 0];
    float q1 = xyz[3 * (size_t)p + 1];
    float q2 = xyz[3 * (size_t)p + 2];
    atomicAdd(&hist[key_of(q0, q1, q2)], 1);
}

// ---------------- counting sort: scan + scatter ----------------

__global__ __launch_bounds__(1024) void scan_k(const int* __restrict__ hist,
                                               int* __restrict__ start) {
    __shared__ int part[1024];
    int t = threadIdx.x;
    int base = t * (NBUCKET / 1024);
    int s = 0;
#pragma unroll 4
    for (int j = 0; j < NBUCKET / 1024; ++j) s += hist[base + j];
    part[t] = s;
    __syncthreads();
    for (int off = 1; off < 1024; off <<= 1) {
        int v = (t >= off) ? part[t - off] : 0;
        __syncthreads();
        part[t] += v;
        __syncthreads();
    }
    int run = (t == 0) ? 0 : part[t - 1];
    for (int j = 0; j < NBUCKET / 1024; ++j) {
        start[base + j] = run;
        run += hist[base + j];
    }
}

__global__ __launch_bounds__(256) void scatter_k(const float* __restrict__ xyz,
                                                 int* __restrict__ start,
                                                 float4* __restrict__ xyzs) {
    int p = blockIdx.x * blockDim.x + threadIdx.x;
    if (p >= NPTS) return;
    float q0 = xyz[3 * (size_t)p + 0];
    float q1 = xyz[3 * (size_t)p + 1];
    float q2 = xyz[3 * (size_t)p + 2];
    int slot = atomicAdd(&start[key_of(q0, q1, q2)], 1);
    float4 v;
    v.x = q0; v.y = q1; v.z = q2; v.w = __int_as_float(p);
    xyzs[slot] = v;
}

// ---------------- MFMA main kernel ----------------

// one mode's worth of MFMAs over the wave's 64-point LDS tile.
// K=48 done as two 16x16x32_bf16: k[0,32) real; k[32,48) real for lanes q<2,
// register-zero for q>=2 (B is also zero there).
__device__ __forceinline__ void mfma_phase(const unsigned short* __restrict__ shw,
                                           int r, int q,
                                           short8 blo0, short8 blo1,
                                           short8 bhi0, short8 bhi1,
                                           floatx4 acc[4][2]) {
    const short8 z8 = {0, 0, 0, 0, 0, 0, 0, 0};
#pragma unroll
    for (int m = 0; m < 4; ++m) {
        const unsigned short* rb = shw + (size_t)(m * 16 + r) * SH_STRIDE;
        short8 alo = *(const short8*)(rb + q * 8);                 // k 0..31
        short8 ahl = *(const short8*)(rb + 32 + (q & 1) * 8);      // k 32..47 (addr clamped)
        short8 ahi = (q < 2) ? ahl : z8;                           // q>=2 -> zero
        acc[m][0] = __builtin_amdgcn_mfma_f32_16x16x32_bf16(alo, blo0, acc[m][0], 0, 0, 0);
        acc[m][0] = __builtin_amdgcn_mfma_f32_16x16x32_bf16(ahi, bhi0, acc[m][0], 0, 0, 0);
        acc[m][1] = __builtin_amdgcn_mfma_f32_16x16x32_bf16(alo, blo1, acc[m][1], 0, 0, 0);
        acc[m][1] = __builtin_amdgcn_mfma_f32_16x16x32_bf16(ahi, bhi1, acc[m][1], 0, 0, 0);
    }
}

constexpr int MAIN_BLK = 128;
constexpr int MAIN_NWG = (NPTS + MAIN_BLK - 1) / MAIN_BLK;   // 7813

// bijective XCD-chunked swizzle (m204)
__device__ __forceinline__ int swz_main(int orig) {
    constexpr int Q = MAIN_NWG / 8, R = MAIN_NWG % 8;   // 976, 5
    int x = orig & 7, p = orig >> 3;
    return (x < R ? x * (Q + 1) : R * (Q + 1) + (x - R) * Q) + p;
}

// lane = (point p, 8-comp slice s) transposed gather: per instruction, lanes
// cover ~11 points x 96B contiguous runs -> ~3x fewer distinct L1 lines than
// the lane=point layout (each lane touching its own row).
__global__ __launch_bounds__(MAIN_BLK, 4) void tensor_vm_mfma_kernel(
    const float4* __restrict__ xyzs,
    const half_t* __restrict__ pt,
    const half_t* __restrict__ lt,
    const unsigned short* __restrict__ wfrag,
    float* __restrict__ out) {
    __shared__ unsigned short sh[2][64][SH_STRIDE];   // product tiles, 14 KB
    __shared__ float          sp[2][64][8];           // per-point params, 4 KB

    const int bid = swz_main(blockIdx.x);
    const int tid = threadIdx.x;
    const int w  = tid >> 6;
    const int ln = tid & 63;
    const int r  = ln & 15;
    const int q  = ln >> 4;
    const int gidx = bid * MAIN_BLK + tid;
    const int i = min(gidx, NPTS - 1);        // clamp (writes guarded below)
    float4 v = xyzs[i];
    const int permInt = __float_as_int(v.w);

    floatx4 acc[4][2];
    const floatx4 z = {0.f, 0.f, 0.f, 0.f};
#pragma unroll
    for (int m = 0; m < 4; ++m) { acc[m][0] = z; acc[m][1] = z; }

    constexpr size_t PSZ = (size_t)RESN * RESN * NCOMP;
    constexpr size_t LSZ = (size_t)RESN * NCOMP;

    const unsigned short* shw = &sh[w][0][0];

    // PLANE_AX = ((2,1),(2,0),(1,0)); line axis = mode index
    const float gxs[3] = {v.z, v.z, v.y};
    const float gys[3] = {v.y, v.x, v.x};
    const float gls[3] = {v.x, v.y, v.z};

#pragma unroll
    for (int md = 0; md < 3; ++md) {
        // B-fragments for this mode (L2-hot 12 KB)
        const unsigned short* wfb = wfrag + (size_t)md * 2048 + (size_t)ln * 8;
        short8 blo0 = *(const short8*)(wfb);           // kblk=0, n=0
        short8 blo1 = *(const short8*)(wfb + 512);     // kblk=0, n=1
        short8 bhi0 = *(const short8*)(wfb + 1024);    // kblk=1, n=0
        short8 bhi1 = *(const short8*)(wfb + 1536);    // kblk=1, n=1

        // ---- owner phase: publish this point's offsets + weights ----
        {
            float x = (gxs[md] + 1.0f) * 0.5f * (float)(RESN - 1);
            float y = (gys[md] + 1.0f) * 0.5f * (float)(RESN - 1);
            float l = (gls[md] + 1.0f) * 0.5f * (float)(RESN - 1);
            float x0f = floorf(x), y0f = floorf(y), l0f = floorf(l);
            float wx = x - x0f, wy = y - y0f, wl = l - l0f;
            int x0 = max(0, min((int)x0f, RESN - 1));
            int y0 = max(0, min((int)y0f, RESN - 1));
            int l0 = max(0, min((int)l0f, RESN - 1));
            int y1 = min(y0 + 1, RESN - 1);
            // byte offsets into this mode's tables; x1/l1 handled as +96B by
            // consumers (clamped cases have zero weight; reads stay in finite data)
            int off0 = (y0 * RESN + x0) * NCOMP * 2;
            int off1 = (y1 * RESN + x0) * NCOMP * 2;
            int offL = l0 * NCOMP * 2;
            float4 A, B;
            A.x = __int_as_float(off0); A.y = __int_as_float(off1);
            A.z = __int_as_float(offL); A.w = (1.0f - wy) * (1.0f - wx);
            B.x = (1.0f - wy) * wx; B.y = wy * (1.0f - wx);
            B.z = wy * wx;          B.w = wl;
            *(float4*)&sp[w][ln][0] = A;
            *(float4*)&sp[w][ln][4] = B;
        }
        __builtin_amdgcn_sched_barrier(0);   // params before consume (in-wave DS is in-order)

        // ---- consume phase: 6 iters, lane -> (p = pair/6, s = pair%6) ----
        const char* pmd = (const char*)(pt + md * PSZ);
        const char* lmd = (const char*)(lt + md * LSZ);
#pragma unroll
        for (int it = 0; it < 6; ++it) {
            unsigned pair = (unsigned)(it * 64 + ln);
            unsigned p = (pair * 10923u) >> 16;      // pair / 6 (exact for pair<384)
            unsigned s = pair - p * 6u;              // pair % 6
            float4 A = *(const float4*)&sp[w][p][0];
            float4 B = *(const float4*)&sp[w][p][4];
            int off0 = __float_as_int(A.x);
            int off1 = __float_as_int(A.y);
            int offL = __float_as_int(A.z);
            float w00 = A.w, w01 = B.x, w10 = B.y, w11 = B.z, wl = B.w;
            int so = (int)(s * 16u);
            half8 a = *(const half8*)(pmd + off0 + so);        // p00 slice
            half8 b = *(const half8*)(pmd + off0 + 96 + so);   // p01 slice
            half8 c = *(const half8*)(pmd + off1 + so);        // p10 slice
            half8 d = *(const half8*)(pmd + off1 + 96 + so);   // p11 slice
            half8 e = *(const half8*)(lmd + offL + so);        // L0 slice
            half8 f = *(const half8*)(lmd + offL + 96 + so);   // L1 slice
            float wl0 = 1.0f - wl;
            ushort8 h;
#pragma unroll
            for (int j = 0; j < 8; ++j) {
                float pv = w00 * (float)a[j] + w01 * (float)b[j]
                         + w10 * (float)c[j] + w11 * (float)d[j];
                float lv = wl0 * (float)e[j] + wl * (float)f[j];
                h[j] = f32_to_bf16(pv * lv);
            }
            *(ushort8*)(&sh[w][p][s * 8u]) = h;
        }

        asm volatile("s_waitcnt lgkmcnt(0)" ::: "memory");
        __builtin_amdgcn_sched_barrier(0);
        mfma_phase(shw, r, q, blo0, blo1, bhi0, bhi1, acc);
        __builtin_amdgcn_sched_barrier(0);   // keep next mode's writes below the reads
    }

    // epilogue: D layout col=lane&15 (feature), row=(lane>>4)*4+reg (point)
    const int blockBase = bid * MAIN_BLK + w * 64;
#pragma unroll
    for (int m = 0; m < 4; ++m) {
#pragma unroll
        for (int rr = 0; rr < 4; ++rr) {
            const int pl = m * 16 + q * 4 + rr;
            const int pp = __shfl(permInt, pl);
            if (blockBase + pl < NPTS) {
                float* o = out + (size_t)pp * NFEAT + r;
                o[0] = acc[m][0][rr];
                if (r < NFEAT - 16) o[16] = acc[m][1][rr];
            }
        }
    }
}

// ---------------- scalar fallbacks ----------------

__device__ __forceinline__ void accum_mode(float gx, float gy, float gl,
                                           const half_t* __restrict__ pt_i,
                                           const half_t* __restrict__ lt_i,
                                           const float* __restrict__ wt_i,
                                           float* __restrict__ acc) {
    float x = (gx + 1.0f) * 0.5f * (float)(RESN - 1);
    float y = (gy + 1.0f) * 0.5f * (float)(RESN - 1);
    float l = (gl + 1.0f) * 0.5f * (float)(RESN - 1);
    float x0f = floorf(x), y0f = floorf(y), l0f = floorf(l);
    float wx = x - x0f, wy = y - y0f, wl = l - l0f;
    int x0 = (int)x0f; x0 = max(0, min(x0, RESN - 1));
    int y0 = (int)y0f; y0 = max(0, min(y0, RESN - 1));
    int l0 = (int)l0f; l0 = max(0, min(l0, RESN - 1));
    int x1 = min(x0 + 1, RESN - 1);
    int y1 = min(y0 + 1, RESN - 1);
    int l1 = min(l0 + 1, RESN - 1);
    float w00 = (1.0f - wy) * (1.0f - wx);
    float w01 = (1.0f - wy) * wx;
    float w10 = wy * (1.0f - wx);
    float w11 = wy * wx;
    float wl0 = 1.0f - wl;
    float wl1 = wl;
    const half8* p00 = (const half8*)(pt_i + ((size_t)y0 * RESN + x0) * NCOMP);
    const half8* p01 = (const half8*)(pt_i + ((size_t)y0 * RESN + x1) * NCOMP);
    const half8* p10 = (const half8*)(pt_i + ((size_t)y1 * RESN + x0) * NCOMP);
    const half8* p11 = (const half8*)(pt_i + ((size_t)y1 * RESN + x1) * NCOMP);
    const half8* L0  = (const half8*)(lt_i + (size_t)l0 * NCOMP);
    const half8* L1  = (const half8*)(lt_i + (size_t)l1 * NCOMP);
#pragma unroll 2
    for (int g = 0; g < NCOMP / 8; ++g) {
        half8 a = p00[g], b = p01[g], c = p10[g], d = p11[g];
        half8 e0 = L0[g], e1 = L1[g];
#pragma unroll
        for (int j = 0; j < 8; ++j) {
            float pv = w00 * (float)a[j] + w01 * (float)b[j]
                     + w10 * (float)c[j] + w11 * (float)d[j];
            float lv = wl0 * (float)e0[j] + wl1 * (float)e1[j];
            float pr = pv * lv;
            const float* wrow = wt_i + (size_t)(8 * g + j) * NFEAT;
#pragma unroll
            for (int f = 0; f < NFEAT; ++f)
                acc[f] += pr * wrow[f];
        }
    }
}

__global__ __launch_bounds__(256) void tensor_vm_kernel(
    const float* __restrict__ xyz,
    const half_t* __restrict__ pt,
    const half_t* __restrict__ lt,
    const float* __restrict__ wt,
    float* __restrict__ out) {
    int p = blockIdx.x * blockDim.x + threadIdx.x;
    if (p >= NPTS) return;
    float q0 = xyz[3 * (size_t)p + 0];
    float q1 = xyz[3 * (size_t)p + 1];
    float q2 = xyz[3 * (size_t)p + 2];
    float acc[NFEAT];
#pragma unroll
    for (int f = 0; f < NFEAT; ++f) acc[f] = 0.0f;
    constexpr size_t PSZ = (size_t)RESN * RESN * NCOMP;
    constexpr size_t LSZ = (size_t)RESN * NCOMP;
    constexpr int    WSZ = NCOMP * NFEAT;
    accum_mode(q2, q1, q0, pt,           lt,           wt,           acc);
    accum_mode(q2, q0, q1, pt + PSZ,     lt + LSZ,     wt + WSZ,     acc);
    accum_mode(q1, q0, q2, pt + 2 * PSZ, lt + 2 * LSZ, wt + 2 * WSZ, acc);
    float* o = out + (size_t)p * NFEAT;
#pragma unroll
    for (int f = 0; f < NFEAT; ++f) o[f] = acc[f];
}

__global__ __launch_bounds__(256) void tensor_vm_naive_kernel(
    const float* __restrict__ xyz,
    const float* __restrict__ planes,
    const float* __restrict__ lines,
    const float* __restrict__ W,
    float* __restrict__ out) {
    int p = blockIdx.x * blockDim.x + threadIdx.x;
    if (p >= NPTS) return;
    float q[3];
    q[0] = xyz[3 * (size_t)p + 0];
    q[1] = xyz[3 * (size_t)p + 1];
    q[2] = xyz[3 * (size_t)p + 2];
    float acc[NFEAT];
    for (int f = 0; f < NFEAT; ++f) acc[f] = 0.0f;
    const int AX[3] = {2, 2, 1};
    const int BX[3] = {1, 0, 0};
    for (int i = 0; i < 3; ++i) {
        float gx = q[AX[i]], gy = q[BX[i]], gl = q[i];
        float x = (gx + 1.0f) * 0.5f * (float)(RESN - 1);
        float y = (gy + 1.0f) * 0.5f * (float)(RESN - 1);
        float l = (gl + 1.0f) * 0.5f * (float)(RESN - 1);
        float x0f = floorf(x), y0f = floorf(y), l0f = floorf(l);
        float wx = x - x0f, wy = y - y0f, wl = l - l0f;
        int x0 = max(0, min((int)x0f, RESN - 1));
        int y0 = max(0, min((int)y0f, RESN - 1));
        int l0 = max(0, min((int)l0f, RESN - 1));
        int x1 = min(x0 + 1, RESN - 1);
        int y1 = min(y0 + 1, RESN - 1);
        int l1 = min(l0 + 1, RESN - 1);
        float w00 = (1.0f - wy) * (1.0f - wx);
        float w01 = (1.0f - wy) * wx;
        float w10 = wy * (1.0f - wx);
        float w11 = wy * wx;
        const float* pl = planes + (size_t)i * NCOMP * RESN * RESN;
        const float* ln = lines + (size_t)i * NCOMP * RESN;
        for (int c = 0; c < NCOMP; ++c) {
            const float* plc = pl + (size_t)c * RESN * RESN;
            float v00 = plc[(size_t)y0 * RESN + x0];
            float v01 = plc[(size_t)y0 * RESN + x1];
            float v10 = plc[(size_t)y1 * RESN + x0];
            float v11 = plc[(size_t)y1 * RESN + x1];
            float pv = w00 * v00 + w01 * v01 + w10 * v10 + w11 * v11;
            float lv = (1.0f - wl) * ln[(size_t)c * RESN + l0] + wl * ln[(size_t)c * RESN + l1];
            float pr = pv * lv;
            int cc = i * NCOMP + c;
            for (int f = 0; f < NFEAT; ++f)
                acc[f] += pr * W[(size_t)f * CCTOT + cc];
        }
    }
    float* o = out + (size_t)p * NFEAT;
    for (int f = 0; f < NFEAT; ++f) o[f] = acc[f];
}

}  // namespace

extern "C" void kernel_launch(void* const* d_in, const int* in_sizes, int n_in,
                              void* d_out, int out_size, void* d_ws, size_t ws_size,
                              hipStream_t stream) {
    (void)in_sizes; (void)n_in; (void)out_size;
    const float* xyz    = (const float*)d_in[0];
    const float* planes = (const float*)d_in[1];
    const float* lines  = (const float*)d_in[2];
    const float* W      = (const float*)d_in[3];
    float* out = (float*)d_out;

    constexpr size_t PT_HALVES   = (size_t)3 * RESN * RESN * NCOMP;  // 12,960,000
    constexpr size_t LT_HALVES   = (size_t)3 * RESN * NCOMP + LT_PAD; // 43,264 (incl pad)
    constexpr size_t WT_FLOATS   = (size_t)CCTOT * NFEAT;            // 3,888

    // ws layout: [wt fp32][wfrag bf16][pt fp16][lt fp16 + pad][hist][start][xyzs]
    constexpr size_t WT_BYTES    = WT_FLOATS * sizeof(float);        // 15,552
    constexpr size_t WFRAG_BYTES = (size_t)WFRAG_TOT * 2;            // 12,288
    constexpr size_t PT_BYTES    = PT_HALVES * sizeof(half_t);       // 25,920,000
    constexpr size_t LT_BYTES    = LT_HALVES * sizeof(half_t);       // 86,528
    constexpr size_t HIST_BYTES  = (size_t)NBUCKET * sizeof(int);    // 131,072
    constexpr size_t XYZS_BYTES  = (size_t)NPTS * sizeof(float4);    // 16,000,000
    constexpr size_t NEED_PLAIN  = WT_BYTES + WFRAG_BYTES + PT_BYTES + LT_BYTES;
    constexpr size_t NEED_SORT   = NEED_PLAIN + 2 * HIST_BYTES + XYZS_BYTES;

    if (ws_size >= NEED_PLAIN) {
        float*          wt    = (float*)d_ws;
        unsigned short* wfrag = (unsigned short*)((char*)d_ws + WT_BYTES);
        half_t*         pt    = (half_t*)((char*)d_ws + WT_BYTES + WFRAG_BYTES);
        half_t*         lt    = (half_t*)((char*)d_ws + WT_BYTES + WFRAG_BYTES + PT_BYTES);
        if (ws_size >= NEED_SORT) {
            int*    hist  = (int*)((char*)d_ws + NEED_PLAIN);
            int*    start = (int*)((char*)d_ws + NEED_PLAIN + HIST_BYTES);
            float4* xyzs  = (float4*)((char*)d_ws + NEED_PLAIN + 2 * HIST_BYTES);
            hipMemsetAsync(hist, 0, HIST_BYTES, stream);
            fused_front_k<<<TP_BLOCKS + SU_BLOCKS + HB_BLOCKS, 256, 0, stream>>>(
                planes, lines, W, xyz, pt, lt, wt, wfrag, hist);
            scan_k<<<1, 1024, 0, stream>>>(hist, start);
            scatter_k<<<(NPTS + 255) / 256, 256, 0, stream>>>(xyz, start, xyzs);
            tensor_vm_mfma_kernel<<<MAIN_NWG, MAIN_BLK, 0, stream>>>(
                xyzs, pt, lt, wfrag, out);
        } else {
            fused_front_k<<<TP_BLOCKS + SU_BLOCKS, 256, 0, stream>>>(
                planes, lines, W, xyz, pt, lt, wt, wfrag, nullptr);
            tensor_vm_kernel<<<(NPTS + 255) / 256, 256, 0, stream>>>(xyz, pt, lt, wt, out);
        }
    } else {
        tensor_vm_naive_kernel<<<(NPTS + 255) / 256, 256, 0, stream>>>(xyz, planes, lines, W, out);
    }
}

// Round 8
// 401.836 us; speedup vs baseline: 1.2239x; 1.0014x over previous
//
#include <hip/hip_runtime.h>

namespace {

constexpr int NCOMP = 48;
constexpr int RESN  = 300;
constexpr int NFEAT = 27;
constexpr int NPTS  = 1000000;
constexpr int CCTOT = 3 * NCOMP;   // 144
constexpr int GRID1 = 32;          // sort cells per axis
constexpr int NBUCKET = GRID1 * GRID1 * GRID1;  // 32768

typedef _Float16 half_t;
typedef __attribute__((ext_vector_type(8))) _Float16 half8;
typedef __attribute__((ext_vector_type(2))) _Float16 half2_t;
typedef __attribute__((ext_vector_type(8))) short          short8;   // 8 bf16 (4 VGPRs)
typedef __attribute__((ext_vector_type(4))) unsigned int   uint4_t;
typedef __attribute__((ext_vector_type(4))) float          floatx4;

// f32 -> bf16 round-to-nearest-even (front-end use)
__device__ __forceinline__ unsigned short f32_to_bf16(float x) {
    unsigned u = __float_as_uint(x);
    u += 0x7fffu + ((u >> 16) & 1u);
    return (unsigned short)(u >> 16);
}

__device__ __forceinline__ half2_t bc_h2(float x) {
    union { float f; half2_t h; } u; u.f = x; return u.h;
}
__device__ __forceinline__ float h2_bc(half2_t h) {
    union { float f; half2_t h; } u; u.h = h; return u.f;
}

// LDS row stride of the MFMA A-tile: 48 bf16 = 96 B (16B-aligned, exact K=48).
constexpr int SH_STRIDE = 48;

// lt gets a 64-half zeroed pad so the l0=299 (+96B) read is safe finite data.
constexpr int LT_PAD = 64;

// ---------------- fused front-end kernel ----------------
constexpr int TP_TOTAL  = 3 * RESN * RESN;          // 270000
constexpr int TP_BLOCKS = (TP_TOTAL + 255) / 256;   // 1055
constexpr int LINES_TOT = 3 * RESN;                 // 900
constexpr int WT_TOT    = NFEAT * CCTOT;            // 3888
constexpr int WFRAG_TOT = 3 * 2 * 2 * 64 * 8;       // 6144
constexpr int SU_TOTAL  = LINES_TOT + WT_TOT + WFRAG_TOT + LT_PAD;  // 10996
constexpr int SU_BLOCKS = (SU_TOTAL + 255) / 256;   // 43
constexpr int HB_BLOCKS = (NPTS + 255) / 256;       // 3907

__device__ __forceinline__ int cell_of(float q) {
    float t = (q + 1.0f) * (0.5f * (float)GRID1);   // [0,32)
    int c = (int)t;
    return min(max(c, 0), GRID1 - 1);
}
__device__ __forceinline__ int key_of(float q0, float q1, float q2) {
    return (cell_of(q0) * GRID1 + cell_of(q1)) * GRID1 + cell_of(q2);
}

__global__ __launch_bounds__(256) void fused_front_k(
    const float* __restrict__ planes, const float* __restrict__ lines,
    const float* __restrict__ W, const float* __restrict__ xyz,
    half_t* __restrict__ pt, half_t* __restrict__ lt,
    float* __restrict__ wt, unsigned short* __restrict__ wfrag,
    int* __restrict__ hist) {
    int b = blockIdx.x;
    if (b < TP_BLOCKS) {
        int idx = b * 256 + threadIdx.x;
        if (idx >= TP_TOTAL) return;
        int i   = idx / (RESN * RESN);
        int rem = idx - i * (RESN * RESN);          // y*RESN + x
        const float* s = planes + (size_t)i * NCOMP * RESN * RESN + rem;
        half8* d = (half8*)(pt + (size_t)idx * NCOMP);
#pragma unroll
        for (int g = 0; g < NCOMP / 8; ++g) {
            half8 h;
#pragma unroll
            for (int k = 0; k < 8; ++k)
                h[k] = (half_t)s[(size_t)(g * 8 + k) * (RESN * RESN)];  // coalesced across lanes
            d[g] = h;
        }
        return;
    }
    if (b < TP_BLOCKS + SU_BLOCKS) {
        int idx = (b - TP_BLOCKS) * 256 + threadIdx.x;
        if (idx < LINES_TOT) {
            int i = idx / RESN;
            int y = idx - i * RESN;
            const float* s = lines + (size_t)i * NCOMP * RESN + y;
            half8* d = (half8*)(lt + (size_t)idx * NCOMP);
#pragma unroll
            for (int g = 0; g < NCOMP / 8; ++g) {
                half8 h;
#pragma unroll
                for (int k = 0; k < 8; ++k)
                    h[k] = (half_t)s[(size_t)(g * 8 + k) * RESN];
                d[g] = h;
            }
            return;
        }
        idx -= LINES_TOT;
        if (idx < WT_TOT) {
            int f  = idx / CCTOT;
            int cc = idx - f * CCTOT;
            wt[(size_t)cc * NFEAT + f] = W[idx];
            return;
        }
        idx -= WT_TOT;
        if (idx < WFRAG_TOT) {
            // [mode][kblk:2][n:2][lane:64][j:8]; value = W[f][mode*48 + kblk*32 + 8*(lane>>4)+j]
            int j    = idx & 7;
            int lane = (idx >> 3) & 63;
            int nn   = (idx >> 9) & 1;
            int kb   = (idx >> 10) & 1;
            int md   = idx >> 11;
            int f  = nn * 16 + (lane & 15);
            int kk = kb * 32 + ((lane >> 4) << 3) + j;
            float vf = 0.0f;
            if (f < NFEAT && kk < NCOMP)
                vf = W[(size_t)f * CCTOT + md * NCOMP + kk];
            wfrag[idx] = f32_to_bf16(vf);
            return;
        }
        idx -= WFRAG_TOT;
        if (idx < LT_PAD) lt[(size_t)3 * RESN * NCOMP + idx] = (half_t)0.f;
        return;
    }
    // histogram
    int p = (b - TP_BLOCKS - SU_BLOCKS) * 256 + threadIdx.x;
    if (p >= NPTS || !hist) return;
    float q0 = xyz[3 * (size_t)p + 0];
    float q1 = xyz[3 * (size_t)p + 1];
    float q2 = xyz[3 * (size_t)p + 2];
    atomicAdd(&hist[key_of(q0, q1, q2)], 1);
}

// ---------------- counting sort: scan + scatter ----------------

__global__ __launch_bounds__(1024) void scan_k(const int* __restrict__ hist,
                                               int* __restrict__ start) {
    __shared__ int part[1024];
    int t = threadIdx.x;
    int base = t * (NBUCKET / 1024);
    int s = 0;
#pragma unroll 4
    for (int j = 0; j < NBUCKET / 1024; ++j) s += hist[base + j];
    part[t] = s;
    __syncthreads();
    for (int off = 1; off < 1024; off <<= 1) {
        int v = (t >= off) ? part[t - off] : 0;
        __syncthreads();
        part[t] += v;
        __syncthreads();
    }
    int run = (t == 0) ? 0 : part[t - 1];
    for (int j = 0; j < NBUCKET / 1024; ++j) {
        start[base + j] = run;
        run += hist[base + j];
    }
}

__global__ __launch_bounds__(256) void scatter_k(const float* __restrict__ xyz,
                                                 int* __restrict__ start,
                                                 float4* __restrict__ xyzs) {
    int p = blockIdx.x * blockDim.x + threadIdx.x;
    if (p >= NPTS) return;
    float q0 = xyz[3 * (size_t)p + 0];
    float q1 = xyz[3 * (size_t)p + 1];
    float q2 = xyz[3 * (size_t)p + 2];
    int slot = atomicAdd(&start[key_of(q0, q1, q2)], 1);
    float4 v;
    v.x = q0; v.y = q1; v.z = q2; v.w = __int_as_float(p);
    xyzs[slot] = v;
}

// ---------------- MFMA main kernel ----------------

// one mode's worth of MFMAs over the wave's 64-point LDS tile.
// K=48 done as two 16x16x32_bf16: k[0,32) real; k[32,48) real for lanes q<2,
// register-zero for q>=2 (B is also zero there).
__device__ __forceinline__ void mfma_phase(const unsigned short* __restrict__ shw,
                                           int r, int q,
                                           short8 blo0, short8 blo1,
                                           short8 bhi0, short8 bhi1,
                                           floatx4 acc[4][2]) {
    const short8 z8 = {0, 0, 0, 0, 0, 0, 0, 0};
#pragma unroll
    for (int m = 0; m < 4; ++m) {
        const unsigned short* rb = shw + (size_t)(m * 16 + r) * SH_STRIDE;
        short8 alo = *(const short8*)(rb + q * 8);                 // k 0..31
        short8 ahl = *(const short8*)(rb + 32 + (q & 1) * 8);      // k 32..47 (addr clamped)
        short8 ahi = (q < 2) ? ahl : z8;                           // q>=2 -> zero
        acc[m][0] = __builtin_amdgcn_mfma_f32_16x16x32_bf16(alo, blo0, acc[m][0], 0, 0, 0);
        acc[m][0] = __builtin_amdgcn_mfma_f32_16x16x32_bf16(ahi, bhi0, acc[m][0], 0, 0, 0);
        acc[m][1] = __builtin_amdgcn_mfma_f32_16x16x32_bf16(alo, blo1, acc[m][1], 0, 0, 0);
        acc[m][1] = __builtin_amdgcn_mfma_f32_16x16x32_bf16(ahi, bhi1, acc[m][1], 0, 0, 0);
    }
}

constexpr int MAIN_BLK = 128;
constexpr int MAIN_NWG = (NPTS + MAIN_BLK - 1) / MAIN_BLK;   // 7813

// bijective XCD-chunked swizzle (m204)
__device__ __forceinline__ int swz_main(int orig) {
    constexpr int Q = MAIN_NWG / 8, R = MAIN_NWG % 8;   // 976, 5
    int x = orig & 7, p = orig >> 3;
    return (x < R ? x * (Q + 1) : R * (Q + 1) + (x - R) * Q) + p;
}

// lane = (point p, 8-comp slice s) transposed gather; interpolation in packed
// fp16 (v_pk_fma_f16) — no per-element f16->f32 converts in the hot loop.
__global__ __launch_bounds__(MAIN_BLK, 4) void tensor_vm_mfma_kernel(
    const float4* __restrict__ xyzs,
    const half_t* __restrict__ pt,
    const half_t* __restrict__ lt,
    const unsigned short* __restrict__ wfrag,
    float* __restrict__ out) {
    __shared__ unsigned short sh[2][64][SH_STRIDE];   // product tiles, 12 KB
    __shared__ float          sp[2][64][8];           // per-point params, 4 KB

    const int bid = swz_main(blockIdx.x);
    const int tid = threadIdx.x;
    const int w  = tid >> 6;
    const int ln = tid & 63;
    const int r  = ln & 15;
    const int q  = ln >> 4;
    const int gidx = bid * MAIN_BLK + tid;
    const int i = min(gidx, NPTS - 1);        // clamp (writes guarded below)
    float4 v = xyzs[i];
    const int permInt = __float_as_int(v.w);

    floatx4 acc[4][2];
    const floatx4 z = {0.f, 0.f, 0.f, 0.f};
#pragma unroll
    for (int m = 0; m < 4; ++m) { acc[m][0] = z; acc[m][1] = z; }

    constexpr size_t PSZ = (size_t)RESN * RESN * NCOMP;
    constexpr size_t LSZ = (size_t)RESN * NCOMP;

    const unsigned short* shw = &sh[w][0][0];

    // PLANE_AX = ((2,1),(2,0),(1,0)); line axis = mode index
    const float gxs[3] = {v.z, v.z, v.y};
    const float gys[3] = {v.y, v.x, v.x};
    const float gls[3] = {v.x, v.y, v.z};

#pragma unroll
    for (int md = 0; md < 3; ++md) {
        // B-fragments for this mode (L2-hot 12 KB)
        const unsigned short* wfb = wfrag + (size_t)md * 2048 + (size_t)ln * 8;
        short8 blo0 = *(const short8*)(wfb);           // kblk=0, n=0
        short8 blo1 = *(const short8*)(wfb + 512);     // kblk=0, n=1
        short8 bhi0 = *(const short8*)(wfb + 1024);    // kblk=1, n=0
        short8 bhi1 = *(const short8*)(wfb + 1536);    // kblk=1, n=1

        // ---- owner phase: publish offsets + duplicated-fp16 lerp weights ----
        {
            float x = (gxs[md] + 1.0f) * 0.5f * (float)(RESN - 1);
            float y = (gys[md] + 1.0f) * 0.5f * (float)(RESN - 1);
            float l = (gls[md] + 1.0f) * 0.5f * (float)(RESN - 1);
            float x0f = floorf(x), y0f = floorf(y), l0f = floorf(l);
            float wx = x - x0f, wy = y - y0f, wl = l - l0f;
            int x0 = max(0, min((int)x0f, RESN - 1));
            int y0 = max(0, min((int)y0f, RESN - 1));
            int l0 = max(0, min((int)l0f, RESN - 1));
            int y1 = min(y0 + 1, RESN - 1);
            int off0 = (y0 * RESN + x0) * NCOMP * 2;
            int off1 = (y1 * RESN + x0) * NCOMP * 2;
            int offL = l0 * NCOMP * 2;
            half_t hx = (half_t)wx, hy = (half_t)wy, hl = (half_t)wl;
            half2_t wx2 = {hx, hx}, wy2 = {hy, hy}, wl2 = {hl, hl};
            float4 A, B;
            A.x = __int_as_float(off0); A.y = __int_as_float(off1);
            A.z = __int_as_float(offL); A.w = h2_bc(wx2);
            B.x = h2_bc(wy2); B.y = h2_bc(wl2); B.z = 0.f; B.w = 0.f;
            *(float4*)&sp[w][ln][0] = A;
            *(float4*)&sp[w][ln][4] = B;
        }
        __builtin_amdgcn_sched_barrier(0);   // params before consume (in-wave DS is in-order)

        // ---- consume phase: 6 iters, lane -> (p = pair/6, s = pair%6) ----
        const char* pmd = (const char*)(pt + md * PSZ);
        const char* lmd = (const char*)(lt + md * LSZ);
#pragma unroll
        for (int it = 0; it < 6; ++it) {
            unsigned pair = (unsigned)(it * 64 + ln);
            unsigned p = (pair * 10923u) >> 16;      // pair / 6 (exact for pair<384)
            unsigned s = pair - p * 6u;              // pair % 6
            float4 A = *(const float4*)&sp[w][p][0];
            float4 B = *(const float4*)&sp[w][p][4];
            int off0 = __float_as_int(A.x);
            int off1 = __float_as_int(A.y);
            int offL = __float_as_int(A.z);
            half2_t wx2 = bc_h2(A.w), wy2 = bc_h2(B.x), wl2 = bc_h2(B.y);
            int so = (int)(s * 16u);
            union H8 { half8 v; half2_t h2[4]; } a, b, c, d, e, f;
            a.v = *(const half8*)(pmd + off0 + so);        // p00 slice
            b.v = *(const half8*)(pmd + off0 + 96 + so);   // p01 slice
            c.v = *(const half8*)(pmd + off1 + so);        // p10 slice
            d.v = *(const half8*)(pmd + off1 + 96 + so);   // p11 slice
            e.v = *(const half8*)(lmd + offL + so);        // L0 slice
            f.v = *(const half8*)(lmd + offL + 96 + so);   // L1 slice
            uint4_t ho;
#pragma unroll
            for (int k = 0; k < 4; ++k) {
                half2_t pa = a.h2[k], pb = b.h2[k], pc = c.h2[k], pd = d.h2[k];
                half2_t px0 = pa + wx2 * (pb - pa);        // v_pk_sub / v_pk_fma
                half2_t px1 = pc + wx2 * (pd - pc);
                half2_t pv  = px0 + wy2 * (px1 - px0);
                half2_t lv  = e.h2[k] + wl2 * (f.h2[k] - e.h2[k]);
                half2_t pr  = pv * lv;
                float f0 = (float)pr[0], f1 = (float)pr[1];
                unsigned o;
                asm("v_cvt_pk_bf16_f32 %0, %1, %2" : "=v"(o) : "v"(f0), "v"(f1));
                ho[k] = o;
            }
            *(uint4_t*)(&sh[w][p][s * 8u]) = ho;
        }

        asm volatile("s_waitcnt lgkmcnt(0)" ::: "memory");
        __builtin_amdgcn_sched_barrier(0);
        mfma_phase(shw, r, q, blo0, blo1, bhi0, bhi1, acc);
        __builtin_amdgcn_sched_barrier(0);   // keep next mode's writes below the reads
    }

    // epilogue: D layout col=lane&15 (feature), row=(lane>>4)*4+reg (point)
    const int blockBase = bid * MAIN_BLK + w * 64;
#pragma unroll
    for (int m = 0; m < 4; ++m) {
#pragma unroll
        for (int rr = 0; rr < 4; ++rr) {
            const int pl = m * 16 + q * 4 + rr;
            const int pp = __shfl(permInt, pl);
            if (blockBase + pl < NPTS) {
                float* o = out + (size_t)pp * NFEAT + r;
                o[0] = acc[m][0][rr];
                if (r < NFEAT - 16) o[16] = acc[m][1][rr];
            }
        }
    }
}

// ---------------- scalar fallbacks ----------------

__device__ __forceinline__ void accum_mode(float gx, float gy, float gl,
                                           const half_t* __restrict__ pt_i,
                                           const half_t* __restrict__ lt_i,
                                           const float* __restrict__ wt_i,
                                           float* __restrict__ acc) {
    float x = (gx + 1.0f) * 0.5f * (float)(RESN - 1);
    float y = (gy + 1.0f) * 0.5f * (float)(RESN - 1);
    float l = (gl + 1.0f) * 0.5f * (float)(RESN - 1);
    float x0f = floorf(x), y0f = floorf(y), l0f = floorf(l);
    float wx = x - x0f, wy = y - y0f, wl = l - l0f;
    int x0 = (int)x0f; x0 = max(0, min(x0, RESN - 1));
    int y0 = (int)y0f; y0 = max(0, min(y0, RESN - 1));
    int l0 = (int)l0f; l0 = max(0, min(l0, RESN - 1));
    int x1 = min(x0 + 1, RESN - 1);
    int y1 = min(y0 + 1, RESN - 1);
    int l1 = min(l0 + 1, RESN - 1);
    float w00 = (1.0f - wy) * (1.0f - wx);
    float w01 = (1.0f - wy) * wx;
    float w10 = wy * (1.0f - wx);
    float w11 = wy * wx;
    float wl0 = 1.0f - wl;
    float wl1 = wl;
    const half8* p00 = (const half8*)(pt_i + ((size_t)y0 * RESN + x0) * NCOMP);
    const half8* p01 = (const half8*)(pt_i + ((size_t)y0 * RESN + x1) * NCOMP);
    const half8* p10 = (const half8*)(pt_i + ((size_t)y1 * RESN + x0) * NCOMP);
    const half8* p11 = (const half8*)(pt_i + ((size_t)y1 * RESN + x1) * NCOMP);
    const half8* L0  = (const half8*)(lt_i + (size_t)l0 * NCOMP);
    const half8* L1  = (const half8*)(lt_i + (size_t)l1 * NCOMP);
#pragma unroll 2
    for (int g = 0; g < NCOMP / 8; ++g) {
        half8 a = p00[g], b = p01[g], c = p10[g], d = p11[g];
        half8 e0 = L0[g], e1 = L1[g];
#pragma unroll
        for (int j = 0; j < 8; ++j) {
            float pv = w00 * (float)a[j] + w01 * (float)b[j]
                     + w10 * (float)c[j] + w11 * (float)d[j];
            float lv = wl0 * (float)e0[j] + wl1 * (float)e1[j];
            float pr = pv * lv;
            const float* wrow = wt_i + (size_t)(8 * g + j) * NFEAT;
#pragma unroll
            for (int f = 0; f < NFEAT; ++f)
                acc[f] += pr * wrow[f];
        }
    }
}

__global__ __launch_bounds__(256) void tensor_vm_kernel(
    const float* __restrict__ xyz,
    const half_t* __restrict__ pt,
    const half_t* __restrict__ lt,
    const float* __restrict__ wt,
    float* __restrict__ out) {
    int p = blockIdx.x * blockDim.x + threadIdx.x;
    if (p >= NPTS) return;
    float q0 = xyz[3 * (size_t)p + 0];
    float q1 = xyz[3 * (size_t)p + 1];
    float q2 = xyz[3 * (size_t)p + 2];
    float acc[NFEAT];
#pragma unroll
    for (int f = 0; f < NFEAT; ++f) acc[f] = 0.0f;
    constexpr size_t PSZ = (size_t)RESN * RESN * NCOMP;
    constexpr size_t LSZ = (size_t)RESN * NCOMP;
    constexpr int    WSZ = NCOMP * NFEAT;
    accum_mode(q2, q1, q0, pt,           lt,           wt,           acc);
    accum_mode(q2, q0, q1, pt + PSZ,     lt + LSZ,     wt + WSZ,     acc);
    accum_mode(q1, q0, q2, pt + 2 * PSZ, lt + 2 * LSZ, wt + 2 * WSZ, acc);
    float* o = out + (size_t)p * NFEAT;
#pragma unroll
    for (int f = 0; f < NFEAT; ++f) o[f] = acc[f];
}

__global__ __launch_bounds__(256) void tensor_vm_naive_kernel(
    const float* __restrict__ xyz,
    const float* __restrict__ planes,
    const float* __restrict__ lines,
    const float* __restrict__ W,
    float* __restrict__ out) {
    int p = blockIdx.x * blockDim.x + threadIdx.x;
    if (p >= NPTS) return;
    float q[3];
    q[0] = xyz[3 * (size_t)p + 0];
    q[1] = xyz[3 * (size_t)p + 1];
    q[2] = xyz[3 * (size_t)p + 2];
    float acc[NFEAT];
    for (int f = 0; f < NFEAT; ++f) acc[f] = 0.0f;
    const int AX[3] = {2, 2, 1};
    const int BX[3] = {1, 0, 0};
    for (int i = 0; i < 3; ++i) {
        float gx = q[AX[i]], gy = q[BX[i]], gl = q[i];
        float x = (gx + 1.0f) * 0.5f * (float)(RESN - 1);
        float y = (gy + 1.0f) * 0.5f * (float)(RESN - 1);
        float l = (gl + 1.0f) * 0.5f * (float)(RESN - 1);
        float x0f = floorf(x), y0f = floorf(y), l0f = floorf(l);
        float wx = x - x0f, wy = y - y0f, wl = l - l0f;
        int x0 = max(0, min((int)x0f, RESN - 1));
        int y0 = max(0, min((int)y0f, RESN - 1));
        int l0 = max(0, min((int)l0f, RESN - 1));
        int x1 = min(x0 + 1, RESN - 1);
        int y1 = min(y0 + 1, RESN - 1);
        int l1 = min(l0 + 1, RESN - 1);
        float w00 = (1.0f - wy) * (1.0f - wx);
        float w01 = (1.0f - wy) * wx;
        float w10 = wy * (1.0f - wx);
        float w11 = wy * wx;
        const float* pl = planes + (size_t)i * NCOMP * RESN * RESN;
        const float* ln = lines + (size_t)i * NCOMP * RESN;
        for (int c = 0; c < NCOMP; ++c) {
            const float* plc = pl + (size_t)c * RESN * RESN;
            float v00 = plc[(size_t)y0 * RESN + x0];
            float v01 = plc[(size_t)y0 * RESN + x1];
            float v10 = plc[(size_t)y1 * RESN + x0];
            float v11 = plc[(size_t)y1 * RESN + x1];
            float pv = w00 * v00 + w01 * v01 + w10 * v10 + w11 * v11;
            float lv = (1.0f - wl) * ln[(size_t)c * RESN + l0] + wl * ln[(size_t)c * RESN + l1];
            float pr = pv * lv;
            int cc = i * NCOMP + c;
            for (int f = 0; f < NFEAT; ++f)
                acc[f] += pr * W[(size_t)f * CCTOT + cc];
        }
    }
    float* o = out + (size_t)p * NFEAT;
    for (int f = 0; f < NFEAT; ++f) o[f] = acc[f];
}

}  // namespace

extern "C" void kernel_launch(void* const* d_in, const int* in_sizes, int n_in,
                              void* d_out, int out_size, void* d_ws, size_t ws_size,
                              hipStream_t stream) {
    (void)in_sizes; (void)n_in; (void)out_size;
    const float* xyz    = (const float*)d_in[0];
    const float* planes = (const float*)d_in[1];
    const float* lines  = (const float*)d_in[2];
    const float* W      = (const float*)d_in[3];
    float* out = (float*)d_out;

    constexpr size_t PT_HALVES   = (size_t)3 * RESN * RESN * NCOMP;  // 12,960,000
    constexpr size_t LT_HALVES   = (size_t)3 * RESN * NCOMP + LT_PAD; // 43,264 (incl pad)
    constexpr size_t WT_FLOATS   = (size_t)CCTOT * NFEAT;            // 3,888

    // ws layout: [wt fp32][wfrag bf16][pt fp16][lt fp16 + pad][hist][start][xyzs]
    constexpr size_t WT_BYTES    = WT_FLOATS * sizeof(float);        // 15,552
    constexpr size_t WFRAG_BYTES = (size_t)WFRAG_TOT * 2;            // 12,288
    constexpr size_t PT_BYTES    = PT_HALVES * sizeof(half_t);       // 25,920,000
    constexpr size_t LT_BYTES    = LT_HALVES * sizeof(half_t);       // 86,528
    constexpr size_t HIST_BYTES  = (size_t)NBUCKET * sizeof(int);    // 131,072
    constexpr size_t XYZS_BYTES  = (size_t)NPTS * sizeof(float4);    // 16,000,000
    constexpr size_t NEED_PLAIN  = WT_BYTES + WFRAG_BYTES + PT_BYTES + LT_BYTES;
    constexpr size_t NEED_SORT   = NEED_PLAIN + 2 * HIST_BYTES + XYZS_BYTES;

    if (ws_size >= NEED_PLAIN) {
        float*          wt    = (float*)d_ws;
        unsigned short* wfrag = (unsigned short*)((char*)d_ws + WT_BYTES);
        half_t*         pt    = (half_t*)((char*)d_ws + WT_BYTES + WFRAG_BYTES);
        half_t*         lt    = (half_t*)((char*)d_ws + WT_BYTES + WFRAG_BYTES + PT_BYTES);
        if (ws_size >= NEED_SORT) {
            int*    hist  = (int*)((char*)d_ws + NEED_PLAIN);
            int*    start = (int*)((char*)d_ws + NEED_PLAIN + HIST_BYTES);
            float4* xyzs  = (float4*)((char*)d_ws + NEED_PLAIN + 2 * HIST_BYTES);
            hipMemsetAsync(hist, 0, HIST_BYTES, stream);
            fused_front_k<<<TP_BLOCKS + SU_BLOCKS + HB_BLOCKS, 256, 0, stream>>>(
                planes, lines, W, xyz, pt, lt, wt, wfrag, hist);
            scan_k<<<1, 1024, 0, stream>>>(hist, start);
            scatter_k<<<(NPTS + 255) / 256, 256, 0, stream>>>(xyz, start, xyzs);
            tensor_vm_mfma_kernel<<<MAIN_NWG, MAIN_BLK, 0, stream>>>(
                xyzs, pt, lt, wfrag, out);
        } else {
            fused_front_k<<<TP_BLOCKS + SU_BLOCKS, 256, 0, stream>>>(
                planes, lines, W, xyz, pt, lt, wt, wfrag, nullptr);
            tensor_vm_kernel<<<(NPTS + 255) / 256, 256, 0, stream>>>(xyz, pt, lt, wt, out);
        }
    } else {
        tensor_vm_naive_kernel<<<(NPTS + 255) / 256, 256, 0, stream>>>(xyz, planes, lines, W, out);
    }
}

// Round 9
// 359.560 us; speedup vs baseline: 1.3678x; 1.1176x over previous
//
#include <hip/hip_runtime.h>

namespace {

constexpr int NCOMP = 48;
constexpr int RESN  = 300;
constexpr int NFEAT = 27;
constexpr int NPTS  = 1000000;
constexpr int CCTOT = 3 * NCOMP;   // 144

typedef _Float16 half_t;
typedef __attribute__((ext_vector_type(8))) _Float16 half8;
typedef __attribute__((ext_vector_type(2))) _Float16 half2_t;
typedef __attribute__((ext_vector_type(8))) short          short8;   // 8 bf16 (4 VGPRs)
typedef __attribute__((ext_vector_type(4))) unsigned int   uint4_t;
typedef __attribute__((ext_vector_type(4))) float          floatx4;

// f32 -> bf16 round-to-nearest-even (front-end use)
__device__ __forceinline__ unsigned short f32_to_bf16(float x) {
    unsigned u = __float_as_uint(x);
    u += 0x7fffu + ((u >> 16) & 1u);
    return (unsigned short)(u >> 16);
}

__device__ __forceinline__ half2_t bc_h2(float x) {
    union { float f; half2_t h; } u; u.f = x; return u.h;
}
__device__ __forceinline__ float h2_bc(half2_t h) {
    union { float f; half2_t h; } u; u.h = h; return u.f;
}

// LDS row stride of the MFMA A-tile: 48 bf16 = 96 B (16B-aligned, exact K=48).
constexpr int SH_STRIDE = 48;

// lt gets a 64-half zeroed pad so the l0=299 (+96B) read is safe finite data.
constexpr int LT_PAD = 64;

// ---------------- fused front-end kernel (NO sort chain) ----------------
constexpr int TP_TOTAL  = 3 * RESN * RESN;          // 270000
constexpr int TP_BLOCKS = (TP_TOTAL + 255) / 256;   // 1055
constexpr int LINES_TOT = 3 * RESN;                 // 900
constexpr int WT_TOT    = NFEAT * CCTOT;            // 3888
constexpr int WFRAG_TOT = 3 * 2 * 2 * 64 * 8;       // 6144
constexpr int SU_TOTAL  = LINES_TOT + WT_TOT + WFRAG_TOT + LT_PAD;  // 10996
constexpr int SU_BLOCKS = (SU_TOTAL + 255) / 256;   // 43

__global__ __launch_bounds__(256) void fused_front_k(
    const float* __restrict__ planes, const float* __restrict__ lines,
    const float* __restrict__ W,
    half_t* __restrict__ pt, half_t* __restrict__ lt,
    float* __restrict__ wt, unsigned short* __restrict__ wfrag) {
    int b = blockIdx.x;
    if (b < TP_BLOCKS) {
        int idx = b * 256 + threadIdx.x;
        if (idx >= TP_TOTAL) return;
        int i   = idx / (RESN * RESN);
        int rem = idx - i * (RESN * RESN);          // y*RESN + x
        const float* s = planes + (size_t)i * NCOMP * RESN * RESN + rem;
        half8* d = (half8*)(pt + (size_t)idx * NCOMP);
#pragma unroll
        for (int g = 0; g < NCOMP / 8; ++g) {
            half8 h;
#pragma unroll
            for (int k = 0; k < 8; ++k)
                h[k] = (half_t)s[(size_t)(g * 8 + k) * (RESN * RESN)];  // coalesced across lanes
            d[g] = h;
        }
        return;
    }
    int idx = (b - TP_BLOCKS) * 256 + threadIdx.x;
    if (idx < LINES_TOT) {
        int i = idx / RESN;
        int y = idx - i * RESN;
        const float* s = lines + (size_t)i * NCOMP * RESN + y;
        half8* d = (half8*)(lt + (size_t)idx * NCOMP);
#pragma unroll
        for (int g = 0; g < NCOMP / 8; ++g) {
            half8 h;
#pragma unroll
            for (int k = 0; k < 8; ++k)
                h[k] = (half_t)s[(size_t)(g * 8 + k) * RESN];
            d[g] = h;
        }
        return;
    }
    idx -= LINES_TOT;
    if (idx < WT_TOT) {
        int f  = idx / CCTOT;
        int cc = idx - f * CCTOT;
        wt[(size_t)cc * NFEAT + f] = W[idx];
        return;
    }
    idx -= WT_TOT;
    if (idx < WFRAG_TOT) {
        // [mode][kblk:2][n:2][lane:64][j:8]; value = W[f][mode*48 + kblk*32 + 8*(lane>>4)+j]
        int j    = idx & 7;
        int lane = (idx >> 3) & 63;
        int nn   = (idx >> 9) & 1;
        int kb   = (idx >> 10) & 1;
        int md   = idx >> 11;
        int f  = nn * 16 + (lane & 15);
        int kk = kb * 32 + ((lane >> 4) << 3) + j;
        float vf = 0.0f;
        if (f < NFEAT && kk < NCOMP)
            vf = W[(size_t)f * CCTOT + md * NCOMP + kk];
        wfrag[idx] = f32_to_bf16(vf);
        return;
    }
    idx -= WFRAG_TOT;
    if (idx < LT_PAD) lt[(size_t)3 * RESN * NCOMP + idx] = (half_t)0.f;
}

// ---------------- MFMA main kernel (unsorted, identity perm) ----------------

// one mode's worth of MFMAs over the wave's 64-point LDS tile.
// K=48 done as two 16x16x32_bf16: k[0,32) real; k[32,48) real for lanes q<2,
// register-zero for q>=2 (B is also zero there).
__device__ __forceinline__ void mfma_phase(const unsigned short* __restrict__ shw,
                                           int r, int q,
                                           short8 blo0, short8 blo1,
                                           short8 bhi0, short8 bhi1,
                                           floatx4 acc[4][2]) {
    const short8 z8 = {0, 0, 0, 0, 0, 0, 0, 0};
#pragma unroll
    for (int m = 0; m < 4; ++m) {
        const unsigned short* rb = shw + (size_t)(m * 16 + r) * SH_STRIDE;
        short8 alo = *(const short8*)(rb + q * 8);                 // k 0..31
        short8 ahl = *(const short8*)(rb + 32 + (q & 1) * 8);      // k 32..47 (addr clamped)
        short8 ahi = (q < 2) ? ahl : z8;                           // q>=2 -> zero
        acc[m][0] = __builtin_amdgcn_mfma_f32_16x16x32_bf16(alo, blo0, acc[m][0], 0, 0, 0);
        acc[m][0] = __builtin_amdgcn_mfma_f32_16x16x32_bf16(ahi, bhi0, acc[m][0], 0, 0, 0);
        acc[m][1] = __builtin_amdgcn_mfma_f32_16x16x32_bf16(alo, blo1, acc[m][1], 0, 0, 0);
        acc[m][1] = __builtin_amdgcn_mfma_f32_16x16x32_bf16(ahi, bhi1, acc[m][1], 0, 0, 0);
    }
}

constexpr int MAIN_BLK = 128;
constexpr int MAIN_NWG = (NPTS + MAIN_BLK - 1) / MAIN_BLK;   // 7813

// lane = (point p, 8-comp slice s) transposed gather; packed-fp16 interpolation.
// No sort: gathers are L3-resident (26 MB table); out writes fully coalesced.
__global__ __launch_bounds__(MAIN_BLK, 4) void tensor_vm_mfma_kernel(
    const float* __restrict__ xyz,
    const half_t* __restrict__ pt,
    const half_t* __restrict__ lt,
    const unsigned short* __restrict__ wfrag,
    float* __restrict__ out) {
    __shared__ unsigned short sh[2][64][SH_STRIDE];   // product tiles, 12 KB
    __shared__ float          sp[2][64][8];           // per-point params, 4 KB

    const int bid = blockIdx.x;
    const int tid = threadIdx.x;
    const int w  = tid >> 6;
    const int ln = tid & 63;
    const int r  = ln & 15;
    const int q  = ln >> 4;
    const int gidx = bid * MAIN_BLK + tid;
    const int i = min(gidx, NPTS - 1);        // clamp (writes guarded below)
    const float q0v = xyz[3 * (size_t)i + 0];
    const float q1v = xyz[3 * (size_t)i + 1];
    const float q2v = xyz[3 * (size_t)i + 2];

    floatx4 acc[4][2];
    const floatx4 z = {0.f, 0.f, 0.f, 0.f};
#pragma unroll
    for (int m = 0; m < 4; ++m) { acc[m][0] = z; acc[m][1] = z; }

    constexpr size_t PSZ = (size_t)RESN * RESN * NCOMP;
    constexpr size_t LSZ = (size_t)RESN * NCOMP;

    const unsigned short* shw = &sh[w][0][0];

    // PLANE_AX = ((2,1),(2,0),(1,0)); line axis = mode index
    const float gxs[3] = {q2v, q2v, q1v};
    const float gys[3] = {q1v, q0v, q0v};
    const float gls[3] = {q0v, q1v, q2v};

#pragma unroll
    for (int md = 0; md < 3; ++md) {
        // B-fragments for this mode (L2-hot 12 KB)
        const unsigned short* wfb = wfrag + (size_t)md * 2048 + (size_t)ln * 8;
        short8 blo0 = *(const short8*)(wfb);           // kblk=0, n=0
        short8 blo1 = *(const short8*)(wfb + 512);     // kblk=0, n=1
        short8 bhi0 = *(const short8*)(wfb + 1024);    // kblk=1, n=0
        short8 bhi1 = *(const short8*)(wfb + 1536);    // kblk=1, n=1

        // ---- owner phase: publish offsets + duplicated-fp16 lerp weights ----
        {
            float x = (gxs[md] + 1.0f) * 0.5f * (float)(RESN - 1);
            float y = (gys[md] + 1.0f) * 0.5f * (float)(RESN - 1);
            float l = (gls[md] + 1.0f) * 0.5f * (float)(RESN - 1);
            float x0f = floorf(x), y0f = floorf(y), l0f = floorf(l);
            float wx = x - x0f, wy = y - y0f, wl = l - l0f;
            int x0 = max(0, min((int)x0f, RESN - 1));
            int y0 = max(0, min((int)y0f, RESN - 1));
            int l0 = max(0, min((int)l0f, RESN - 1));
            int y1 = min(y0 + 1, RESN - 1);
            int off0 = (y0 * RESN + x0) * NCOMP * 2;
            int off1 = (y1 * RESN + x0) * NCOMP * 2;
            int offL = l0 * NCOMP * 2;
            half_t hx = (half_t)wx, hy = (half_t)wy, hl = (half_t)wl;
            half2_t wx2 = {hx, hx}, wy2 = {hy, hy}, wl2 = {hl, hl};
            float4 A, B;
            A.x = __int_as_float(off0); A.y = __int_as_float(off1);
            A.z = __int_as_float(offL); A.w = h2_bc(wx2);
            B.x = h2_bc(wy2); B.y = h2_bc(wl2); B.z = 0.f; B.w = 0.f;
            *(float4*)&sp[w][ln][0] = A;
            *(float4*)&sp[w][ln][4] = B;
        }
        __builtin_amdgcn_sched_barrier(0);   // params before consume (in-wave DS is in-order)

        // ---- consume phase: 6 iters, lane -> (p = pair/6, s = pair%6) ----
        const char* pmd = (const char*)(pt + md * PSZ);
        const char* lmd = (const char*)(lt + md * LSZ);
#pragma unroll
        for (int it = 0; it < 6; ++it) {
            unsigned pair = (unsigned)(it * 64 + ln);
            unsigned p = (pair * 10923u) >> 16;      // pair / 6 (exact for pair<384)
            unsigned s = pair - p * 6u;              // pair % 6
            float4 A = *(const float4*)&sp[w][p][0];
            float4 B = *(const float4*)&sp[w][p][4];
            int off0 = __float_as_int(A.x);
            int off1 = __float_as_int(A.y);
            int offL = __float_as_int(A.z);
            half2_t wx2 = bc_h2(A.w), wy2 = bc_h2(B.x), wl2 = bc_h2(B.y);
            int so = (int)(s * 16u);
            union H8 { half8 v; half2_t h2[4]; } a, b, c, d, e, f;
            a.v = *(const half8*)(pmd + off0 + so);        // p00 slice
            b.v = *(const half8*)(pmd + off0 + 96 + so);   // p01 slice
            c.v = *(const half8*)(pmd + off1 + so);        // p10 slice
            d.v = *(const half8*)(pmd + off1 + 96 + so);   // p11 slice
            e.v = *(const half8*)(lmd + offL + so);        // L0 slice
            f.v = *(const half8*)(lmd + offL + 96 + so);   // L1 slice
            uint4_t ho;
#pragma unroll
            for (int k = 0; k < 4; ++k) {
                half2_t pa = a.h2[k], pb = b.h2[k], pc = c.h2[k], pd = d.h2[k];
                half2_t px0 = pa + wx2 * (pb - pa);        // v_pk_fma chains
                half2_t px1 = pc + wx2 * (pd - pc);
                half2_t pv  = px0 + wy2 * (px1 - px0);
                half2_t lv  = e.h2[k] + wl2 * (f.h2[k] - e.h2[k]);
                half2_t pr  = pv * lv;
                float f0 = (float)pr[0], f1 = (float)pr[1];
                unsigned o;
                asm("v_cvt_pk_bf16_f32 %0, %1, %2" : "=v"(o) : "v"(f0), "v"(f1));
                ho[k] = o;
            }
            *(uint4_t*)(&sh[w][p][s * 8u]) = ho;
        }

        asm volatile("s_waitcnt lgkmcnt(0)" ::: "memory");
        __builtin_amdgcn_sched_barrier(0);
        mfma_phase(shw, r, q, blo0, blo1, bhi0, bhi1, acc);
        __builtin_amdgcn_sched_barrier(0);   // keep next mode's writes below the reads
    }

    // epilogue: D layout col=lane&15 (feature), row=(lane>>4)*4+reg (point)
    // identity perm -> coalesced out writes
    const int blockBase = bid * MAIN_BLK + w * 64;
#pragma unroll
    for (int m = 0; m < 4; ++m) {
#pragma unroll
        for (int rr = 0; rr < 4; ++rr) {
            const int pp = blockBase + m * 16 + q * 4 + rr;
            if (pp < NPTS) {
                float* o = out + (size_t)pp * NFEAT + r;
                o[0] = acc[m][0][rr];
                if (r < NFEAT - 16) o[16] = acc[m][1][rr];
            }
        }
    }
}

// ---------------- scalar fallbacks ----------------

__device__ __forceinline__ void accum_mode(float gx, float gy, float gl,
                                           const half_t* __restrict__ pt_i,
                                           const half_t* __restrict__ lt_i,
                                           const float* __restrict__ wt_i,
                                           float* __restrict__ acc) {
    float x = (gx + 1.0f) * 0.5f * (float)(RESN - 1);
    float y = (gy + 1.0f) * 0.5f * (float)(RESN - 1);
    float l = (gl + 1.0f) * 0.5f * (float)(RESN - 1);
    float x0f = floorf(x), y0f = floorf(y), l0f = floorf(l);
    float wx = x - x0f, wy = y - y0f, wl = l - l0f;
    int x0 = (int)x0f; x0 = max(0, min(x0, RESN - 1));
    int y0 = (int)y0f; y0 = max(0, min(y0, RESN - 1));
    int l0 = (int)l0f; l0 = max(0, min(l0, RESN - 1));
    int x1 = min(x0 + 1, RESN - 1);
    int y1 = min(y0 + 1, RESN - 1);
    int l1 = min(l0 + 1, RESN - 1);
    float w00 = (1.0f - wy) * (1.0f - wx);
    float w01 = (1.0f - wy) * wx;
    float w10 = wy * (1.0f - wx);
    float w11 = wy * wx;
    float wl0 = 1.0f - wl;
    float wl1 = wl;
    const half8* p00 = (const half8*)(pt_i + ((size_t)y0 * RESN + x0) * NCOMP);
    const half8* p01 = (const half8*)(pt_i + ((size_t)y0 * RESN + x1) * NCOMP);
    const half8* p10 = (const half8*)(pt_i + ((size_t)y1 * RESN + x0) * NCOMP);
    const half8* p11 = (const half8*)(pt_i + ((size_t)y1 * RESN + x1) * NCOMP);
    const half8* L0  = (const half8*)(lt_i + (size_t)l0 * NCOMP);
    const half8* L1  = (const half8*)(lt_i + (size_t)l1 * NCOMP);
#pragma unroll 2
    for (int g = 0; g < NCOMP / 8; ++g) {
        half8 a = p00[g], b = p01[g], c = p10[g], d = p11[g];
        half8 e0 = L0[g], e1 = L1[g];
#pragma unroll
        for (int j = 0; j < 8; ++j) {
            float pv = w00 * (float)a[j] + w01 * (float)b[j]
                     + w10 * (float)c[j] + w11 * (float)d[j];
            float lv = wl0 * (float)e0[j] + wl1 * (float)e1[j];
            float pr = pv * lv;
            const float* wrow = wt_i + (size_t)(8 * g + j) * NFEAT;
#pragma unroll
            for (int f = 0; f < NFEAT; ++f)
                acc[f] += pr * wrow[f];
        }
    }
}

__global__ __launch_bounds__(256) void tensor_vm_kernel(
    const float* __restrict__ xyz,
    const half_t* __restrict__ pt,
    const half_t* __restrict__ lt,
    const float* __restrict__ wt,
    float* __restrict__ out) {
    int p = blockIdx.x * blockDim.x + threadIdx.x;
    if (p >= NPTS) return;
    float q0 = xyz[3 * (size_t)p + 0];
    float q1 = xyz[3 * (size_t)p + 1];
    float q2 = xyz[3 * (size_t)p + 2];
    float acc[NFEAT];
#pragma unroll
    for (int f = 0; f < NFEAT; ++f) acc[f] = 0.0f;
    constexpr size_t PSZ = (size_t)RESN * RESN * NCOMP;
    constexpr size_t LSZ = (size_t)RESN * NCOMP;
    constexpr int    WSZ = NCOMP * NFEAT;
    accum_mode(q2, q1, q0, pt,           lt,           wt,           acc);
    accum_mode(q2, q0, q1, pt + PSZ,     lt + LSZ,     wt + WSZ,     acc);
    accum_mode(q1, q0, q2, pt + 2 * PSZ, lt + 2 * LSZ, wt + 2 * WSZ, acc);
    float* o = out + (size_t)p * NFEAT;
#pragma unroll
    for (int f = 0; f < NFEAT; ++f) o[f] = acc[f];
}

__global__ __launch_bounds__(256) void tensor_vm_naive_kernel(
    const float* __restrict__ xyz,
    const float* __restrict__ planes,
    const float* __restrict__ lines,
    const float* __restrict__ W,
    float* __restrict__ out) {
    int p = blockIdx.x * blockDim.x + threadIdx.x;
    if (p >= NPTS) return;
    float q[3];
    q[0] = xyz[3 * (size_t)p + 0];
    q[1] = xyz[3 * (size_t)p + 1];
    q[2] = xyz[3 * (size_t)p + 2];
    float acc[NFEAT];
    for (int f = 0; f < NFEAT; ++f) acc[f] = 0.0f;
    const int AX[3] = {2, 2, 1};
    const int BX[3] = {1, 0, 0};
    for (int i = 0; i < 3; ++i) {
        float gx = q[AX[i]], gy = q[BX[i]], gl = q[i];
        float x = (gx + 1.0f) * 0.5f * (float)(RESN - 1);
        float y = (gy + 1.0f) * 0.5f * (float)(RESN - 1);
        float l = (gl + 1.0f) * 0.5f * (float)(RESN - 1);
        float x0f = floorf(x), y0f = floorf(y), l0f = floorf(l);
        float wx = x - x0f, wy = y - y0f, wl = l - l0f;
        int x0 = max(0, min((int)x0f, RESN - 1));
        int y0 = max(0, min((int)y0f, RESN - 1));
        int l0 = max(0, min((int)l0f, RESN - 1));
        int x1 = min(x0 + 1, RESN - 1);
        int y1 = min(y0 + 1, RESN - 1);
        int l1 = min(l0 + 1, RESN - 1);
        float w00 = (1.0f - wy) * (1.0f - wx);
        float w01 = (1.0f - wy) * wx;
        float w10 = wy * (1.0f - wx);
        float w11 = wy * wx;
        const float* pl = planes + (size_t)i * NCOMP * RESN * RESN;
        const float* ln = lines + (size_t)i * NCOMP * RESN;
        for (int c = 0; c < NCOMP; ++c) {
            const float* plc = pl + (size_t)c * RESN * RESN;
            float v00 = plc[(size_t)y0 * RESN + x0];
            float v01 = plc[(size_t)y0 * RESN + x1];
            float v10 = plc[(size_t)y1 * RESN + x0];
            float v11 = plc[(size_t)y1 * RESN + x1];
            float pv = w00 * v00 + w01 * v01 + w10 * v10 + w11 * v11;
            float lv = (1.0f - wl) * ln[(size_t)c * RESN + l0] + wl * ln[(size_t)c * RESN + l1];
            float pr = pv * lv;
            int cc = i * NCOMP + c;
            for (int f = 0; f < NFEAT; ++f)
                acc[f] += pr * W[(size_t)f * CCTOT + cc];
        }
    }
    float* o = out + (size_t)p * NFEAT;
    for (int f = 0; f < NFEAT; ++f) o[f] = acc[f];
}

}  // namespace

extern "C" void kernel_launch(void* const* d_in, const int* in_sizes, int n_in,
                              void* d_out, int out_size, void* d_ws, size_t ws_size,
                              hipStream_t stream) {
    (void)in_sizes; (void)n_in; (void)out_size;
    const float* xyz    = (const float*)d_in[0];
    const float* planes = (const float*)d_in[1];
    const float* lines  = (const float*)d_in[2];
    const float* W      = (const float*)d_in[3];
    float* out = (float*)d_out;

    constexpr size_t PT_HALVES   = (size_t)3 * RESN * RESN * NCOMP;   // 12,960,000
    constexpr size_t LT_HALVES   = (size_t)3 * RESN * NCOMP + LT_PAD; // 43,264 (incl pad)
    constexpr size_t WT_FLOATS   = (size_t)CCTOT * NFEAT;             // 3,888

    // ws layout: [wt fp32][wfrag bf16][pt fp16][lt fp16 + pad]
    constexpr size_t WT_BYTES    = WT_FLOATS * sizeof(float);         // 15,552
    constexpr size_t WFRAG_BYTES = (size_t)WFRAG_TOT * 2;             // 12,288
    constexpr size_t PT_BYTES    = PT_HALVES * sizeof(half_t);        // 25,920,000
    constexpr size_t LT_BYTES    = LT_HALVES * sizeof(half_t);        // 86,528
    constexpr size_t NEED_PLAIN  = WT_BYTES + WFRAG_BYTES + PT_BYTES + LT_BYTES;

    if (ws_size >= NEED_PLAIN) {
        float*          wt    = (float*)d_ws;
        unsigned short* wfrag = (unsigned short*)((char*)d_ws + WT_BYTES);
        half_t*         pt    = (half_t*)((char*)d_ws + WT_BYTES + WFRAG_BYTES);
        half_t*         lt    = (half_t*)((char*)d_ws + WT_BYTES + WFRAG_BYTES + PT_BYTES);
        fused_front_k<<<TP_BLOCKS + SU_BLOCKS, 256, 0, stream>>>(
            planes, lines, W, pt, lt, wt, wfrag);
        tensor_vm_mfma_kernel<<<MAIN_NWG, MAIN_BLK, 0, stream>>>(
            xyz, pt, lt, wfrag, out);
    } else {
        tensor_vm_naive_kernel<<<(NPTS + 255) / 256, 256, 0, stream>>>(xyz, planes, lines, W, out);
    }
}